// Round 14
// baseline (648.547 us; speedup 1.0000x reference)
//
#include <hip/hip_runtime.h>

// AutoEncoder v14, bf16 MFMA (gfx950).
// L1: v9 kernel. L2+L3+L4+L5 fused into `quad` (h2/h3/h4 in LDS, only
// actP-in / actH-out touch HBM). L6: single-pass BN=896 BK=32 kernel.

typedef short bf16x8 __attribute__((ext_vector_type(8)));
typedef float f32x4  __attribute__((ext_vector_type(4)));

#define B_ROWS 65536
#define EPS_LN 1e-5f

static __device__ __forceinline__ unsigned short f2bf(float f) {
    union { float f; unsigned u; } v; v.f = f;
    unsigned r = v.u + 0x7FFFu + ((v.u >> 16) & 1u);   // RNE
    return (unsigned short)(r >> 16);
}

static __device__ __forceinline__ float mish_f(float x) {
    if (x > 15.f) return x;
    float u = __expf(x);
    float p = __fmaf_rn(u, u, 2.f * u);
    return x * (p / (p + 2.f));
}

// direct global->LDS, 16B per lane; LDS base must be wave-uniform
static __device__ __forceinline__ void glds16(const void* g, void* l) {
    typedef __attribute__((address_space(3))) unsigned lds_u32;
    typedef __attribute__((address_space(1))) const unsigned glb_u32;
    lds_u32* lp = (lds_u32*)l;
    unsigned lofs = __builtin_amdgcn_readfirstlane((unsigned)(unsigned long long)lp);
    lp = (lds_u32*)(unsigned long long)lofs;
    __builtin_amdgcn_global_load_lds((glb_u32*)g, lp, 16, 0, 0);
}

// ---------------- padded weight fp32->bf16 conversion ----------------
struct CvtArgs {
    const float* src[6];
    unsigned short* dst[6];
    int O[6], K[6], KP[6];
    int base[7];
};

__global__ void wpad_kernel(CvtArgs a) {
    int b = blockIdx.x;
    int seg = 0;
    while (b >= a.base[seg + 1]) ++seg;
    int r = b - a.base[seg];
    int O = a.O[seg], K = a.K[seg], KP = a.KP[seg];
    const float* s = a.src[seg];
    unsigned short* d = a.dst[seg];
    for (int c = threadIdx.x; c < KP; c += 256) {
        unsigned short v = 0;
        if (r < O && c < K) v = f2bf(s[(size_t)r * K + c]);
        d[(size_t)r * KP + c] = v;
    }
}

// ---------------- v9 fused layer kernel (BK=64) — used for L1 ----------------
template<int KP, int ASTR, int BN, int OREAL, int OSTRIDE, int NKT,
         bool SRCF32, bool HASBIAS, bool ABS, bool LN>
__global__ __launch_bounds__(512, 2)
void layer9(const void* __restrict__ Asrc,
            const unsigned short* __restrict__ Wp,
            const float* __restrict__ gam,
            const float* __restrict__ bet,
            const float* __restrict__ bias,
            void* __restrict__ Aout,
            float* __restrict__ partials)
{
    constexpr int NT   = BN / 64;
    constexpr int NCHW = BN / 8;
    constexpr int NCH  = NCHW + (SRCF32 ? 0 : 16);
    constexpr int MAXC = (NCH + 7) / 8;
    constexpr int ABY  = 128 * 128;
    constexpr int WBY  = BN * 128;

    __shared__ __align__(16) char smem[2 * ABY + 2 * WBY];

    const int tid  = threadIdx.x;
    const int lane = tid & 63;
    const int wu   = __builtin_amdgcn_readfirstlane(tid >> 6);
    const int wr = wu >> 2, wc = wu & 3;
    const int lg = lane >> 4, lc = lane & 15;
    const int row0  = blockIdx.x * 128;
    const int cbase = LN ? 0 : blockIdx.y * BN;

    const int crow = lane >> 3;
    const int sg   = (lane & 7) ^ crow;
    const size_t vofW = ((size_t)crow * KP + (size_t)(sg << 3)) * 2;
    const size_t vofA = ((size_t)crow * ASTR + (size_t)(sg << 3)) * 2;

    auto stage = [&](int t, int b) {
#pragma unroll
        for (int i = 0; i < MAXC; ++i) {
            int c = wu + 8 * i;
            if (c < NCHW) {
                const char* g = (const char*)Wp +
                    ((size_t)(cbase + c * 8) * KP) * 2 + (size_t)t * 128 + vofW;
                glds16(g, smem + (2 * ABY + b * WBY + c * 1024));
            } else if (c < NCH) {
                int ca = c - NCHW;
                const char* g = (const char*)Asrc +
                    ((size_t)(row0 + ca * 8) * ASTR) * 2 + (size_t)t * 128 + vofA;
                glds16(g, smem + (b * ABY + ca * 1024));
            }
        }
    };

    const int ar = tid >> 2, as = tid & 3;
    const float* axp = (const float*)Asrc + (size_t)(row0 + ar) * ASTR + as * 16;
    float4 rA[4];
#pragma unroll
    for (int j = 0; j < 4; ++j) rA[j] = make_float4(0, 0, 0, 0);

    auto loadA1 = [&](int t) {
#pragma unroll
        for (int j = 0; j < 4; ++j) {
            int c0 = t * 64 + as * 16 + j * 4;
            rA[j] = (c0 + 3 < 784) ? *(const float4*)(axp + t * 64 + j * 4)
                                   : make_float4(0, 0, 0, 0);
        }
    };
    auto pubA = [&](int b) {
        union { unsigned short us[8]; uint4 v; } u0, u1;
        u0.us[0] = f2bf(rA[0].x); u0.us[1] = f2bf(rA[0].y);
        u0.us[2] = f2bf(rA[0].z); u0.us[3] = f2bf(rA[0].w);
        u0.us[4] = f2bf(rA[1].x); u0.us[5] = f2bf(rA[1].y);
        u0.us[6] = f2bf(rA[1].z); u0.us[7] = f2bf(rA[1].w);
        u1.us[0] = f2bf(rA[2].x); u1.us[1] = f2bf(rA[2].y);
        u1.us[2] = f2bf(rA[2].z); u1.us[3] = f2bf(rA[2].w);
        u1.us[4] = f2bf(rA[3].x); u1.us[5] = f2bf(rA[3].y);
        u1.us[6] = f2bf(rA[3].z); u1.us[7] = f2bf(rA[3].w);
        int s0 = as * 2, rb = b * ABY + ar * 128, rx = ar & 7;
        *(uint4*)(smem + rb + (((s0    ) ^ rx) << 4)) = u0.v;
        *(uint4*)(smem + rb + (((s0 + 1) ^ rx) << 4)) = u1.v;
    };

    stage(0, 0);
    if constexpr (SRCF32) { loadA1(0); pubA(0); }
    __syncthreads();

    f32x4 acc[4][NT];
#pragma unroll
    for (int a = 0; a < 4; ++a)
#pragma unroll
        for (int c = 0; c < NT; ++c) acc[a][c] = (f32x4){0.f, 0.f, 0.f, 0.f};

    const int f0 = ((lg ^ (lc & 7)) << 4);

    for (int t = 0; t < NKT; ++t) {
        const int bsel = t & 1;
        if (t + 1 < NKT) {
            stage(t + 1, bsel ^ 1);
            if constexpr (SRCF32) loadA1(t + 1);
        }
        const char* Ab = smem + bsel * ABY + (wr * 64 + lc) * 128;
        const char* Bb = smem + 2 * ABY + bsel * WBY + (wc * NT * 16 + lc) * 128;
#pragma unroll
        for (int h = 0; h < 2; ++h) {
            const int fh = f0 ^ (h << 6);
            bf16x8 afr[4], bfr[NT];
#pragma unroll
            for (int a = 0; a < 4; ++a)
                afr[a] = *(const bf16x8*)(Ab + a * 2048 + fh);
#pragma unroll
            for (int c = 0; c < NT; ++c)
                bfr[c] = *(const bf16x8*)(Bb + c * 2048 + fh);
            __builtin_amdgcn_s_setprio(1);
#pragma unroll
            for (int c = 0; c < NT; ++c)
#pragma unroll
                for (int a = 0; a < 4; ++a)
                    acc[a][c] = __builtin_amdgcn_mfma_f32_16x16x32_bf16(afr[a], bfr[c], acc[a][c], 0, 0, 0);
            __builtin_amdgcn_s_setprio(0);
        }
        if constexpr (SRCF32) { if (t + 1 < NKT) pubA(bsel ^ 1); }
        __syncthreads();
    }

    if constexpr (LN) {
        if constexpr (HASBIAS) {
#pragma unroll
            for (int c = 0; c < NT; ++c) {
                int col = wc * NT * 16 + c * 16 + lc;
                float bv = (col < OREAL) ? bias[col] : 0.f;
#pragma unroll
                for (int a = 0; a < 4; ++a)
#pragma unroll
                    for (int r = 0; r < 4; ++r) acc[a][c][r] += bv;
            }
        }
        float ps1[4][4], ps2[4][4];
#pragma unroll
        for (int a = 0; a < 4; ++a)
#pragma unroll
            for (int r = 0; r < 4; ++r) { ps1[a][r] = 0.f; ps2[a][r] = 0.f; }
#pragma unroll
        for (int a = 0; a < 4; ++a)
#pragma unroll
            for (int c = 0; c < NT; ++c)
#pragma unroll
                for (int r = 0; r < 4; ++r) {
                    float v = acc[a][c][r];
                    ps1[a][r] += v;
                    ps2[a][r] = __fmaf_rn(v, v, ps2[a][r]);
                }
#pragma unroll
        for (int m = 1; m < 16; m <<= 1)
#pragma unroll
            for (int a = 0; a < 4; ++a)
#pragma unroll
                for (int r = 0; r < 4; ++r) {
                    ps1[a][r] += __shfl_xor(ps1[a][r], m);
                    ps2[a][r] += __shfl_xor(ps2[a][r], m);
                }

        float* lnP  = (float*)smem;
        float* lnMR = (float*)(smem + 4096);
        float* wsum = (float*)(smem + 5120);

        if (lc == 0) {
#pragma unroll
            for (int a = 0; a < 4; ++a)
#pragma unroll
                for (int r = 0; r < 4; ++r) {
                    int row = wr * 64 + a * 16 + lg * 4 + r;
                    lnP[row * 4 + wc]       = ps1[a][r];
                    lnP[512 + row * 4 + wc] = ps2[a][r];
                }
        }
        __syncthreads();
        if (tid < 128) {
            float s1 = lnP[tid * 4] + lnP[tid * 4 + 1] + lnP[tid * 4 + 2] + lnP[tid * 4 + 3];
            float s2 = lnP[512 + tid * 4] + lnP[512 + tid * 4 + 1] +
                       lnP[512 + tid * 4 + 2] + lnP[512 + tid * 4 + 3];
            float mu = s1 * (1.f / OREAL);
            float var = fmaxf(s2 * (1.f / OREAL) - mu * mu, 0.f);
            lnMR[tid]       = mu;
            lnMR[128 + tid] = rsqrtf(var + EPS_LN);
        }
        __syncthreads();

        float gcol[NT], bcol[NT];
#pragma unroll
        for (int c = 0; c < NT; ++c) {
            int col = wc * NT * 16 + c * 16 + lc;
            gcol[c] = (col < OREAL) ? gam[col] : 0.f;
            bcol[c] = (col < OREAL) ? bet[col] : 0.f;
        }

        float asum = 0.f;
        unsigned short* outp = (unsigned short*)Aout;
#pragma unroll
        for (int a = 0; a < 4; ++a)
#pragma unroll
            for (int r = 0; r < 4; ++r) {
                int rl = wr * 64 + a * 16 + lg * 4 + r;
                float mu = lnMR[rl], rs = lnMR[128 + rl];
                size_t rowoff = (size_t)(row0 + rl) * OSTRIDE;
#pragma unroll
                for (int c = 0; c < NT; ++c) {
                    int col = wc * NT * 16 + c * 16 + lc;
                    if (col < OSTRIDE) {
                        unsigned short outv = 0;
                        if (col < OREAL) {
                            float v = (acc[a][c][r] - mu) * rs * gcol[c] + bcol[c];
                            float mz = mish_f(v);
                            if (ABS) asum += fabsf(mz);
                            outv = f2bf(mz);
                        }
                        outp[rowoff + col] = outv;
                    }
                }
            }

        if constexpr (ABS) {
#pragma unroll
            for (int m = 1; m < 64; m <<= 1) asum += __shfl_xor(asum, m);
            if (lane == 0) wsum[wu] = asum;
            __syncthreads();
            if (tid == 0) {
                float s = 0.f;
                for (int w = 0; w < 8; ++w) s += wsum[w];
                partials[blockIdx.x] = s;
            }
        }
    } else {
        float* outp = (float*)Aout;
#pragma unroll
        for (int c = 0; c < NT; ++c) {
            int col = cbase + wc * NT * 16 + c * 16 + lc;
            bool ok = col < OREAL;
            float bv = ok ? bias[col] : 0.f;
#pragma unroll
            for (int a = 0; a < 4; ++a)
#pragma unroll
                for (int r = 0; r < 4; ++r) {
                    if (ok) {
                        int rl = wr * 64 + a * 16 + lg * 4 + r;
                        float v = acc[a][c][r] + bv;
                        outp[(size_t)(row0 + rl) * OSTRIDE + col] = 1.f / (1.f + __expf(-v));
                    }
                }
        }
    }
}

// ---------------- quad kernel: L2+L3+L4+L5 fused, activations in LDS ----------------
// Block 512 thr = 8 waves (2x4), 128-row tile, BK=32.
// LDS lifetime map (bytes):
//  G1: A1 dbuf [0,16K)      W2 dbuf [16K,64K)   h2 -> [64K,136K) str 576
//  G2: W3 dbuf [0,16K)      h2 in   [64K,136K)  h3 -> [120K,152K) str 256
//  G3: D1 dbuf [0,48K)      h3 in   [120K,152K) h4 -> [48K,120K)  str 576
//  G4: W5 sbuf [120K,152K)  h4 in   [48K,120K)  out -> actH global
//  LN scratch: [152K, 152K+5.2K)  (dedicated, all phases)
#define H2_OFF  65536
#define H3_OFF  122880
#define H4_OFF  49152
#define W5_OFF  122880
#define LN_OFF  155648

__global__ __launch_bounds__(512, 2)
void quad(const unsigned short* __restrict__ actP,
          const unsigned short* __restrict__ W2p,   // [384][512]
          const unsigned short* __restrict__ W3p,   // [128][288]
          const unsigned short* __restrict__ D1p,   // [384][128]
          const unsigned short* __restrict__ D2p,   // [512][320]
          const float* __restrict__ g2, const float* __restrict__ b2,
          const float* __restrict__ gh, const float* __restrict__ bh,
          const float* __restrict__ b3,
          const float* __restrict__ g3, const float* __restrict__ b3n,
          const float* __restrict__ g4, const float* __restrict__ b4,
          unsigned short* __restrict__ actH,        // [B][512]
          float* __restrict__ partials)
{
    __shared__ __align__(16) char smem[160800];

    const int tid  = threadIdx.x;
    const int lane = tid & 63;
    const int wu   = __builtin_amdgcn_readfirstlane(tid >> 6);
    const int wr = wu >> 2, wc = wu & 3;
    const int lg = lane >> 4, lc = lane & 15;
    const int row0 = blockIdx.x * 128;

    const int sgl = (lane & 3) ^ ((lane >> 3) & 3);      // BK=32 chunk swizzle
    const size_t vofA  = ((size_t)(lane >> 2) * 512 + (size_t)(sgl << 3)) * 2;
    const size_t vofW2 = vofA;                            // KP=512
    const size_t vofW3 = ((size_t)(lane >> 2) * 288 + (size_t)(sgl << 3)) * 2;
    const size_t vofD1 = ((size_t)(lane >> 2) * 128 + (size_t)(sgl << 3)) * 2;
    const size_t vofW5 = ((size_t)(lane >> 2) * 320 + (size_t)(sgl << 3)) * 2;

    const int fswz = ((lg ^ ((lc >> 1) & 3)) << 4);

    float* lnP  = (float*)(smem + LN_OFF);          // [128][4] s1 | s2
    float* lnMR = (float*)(smem + LN_OFF + 4096);   // [256]
    float* wsum = (float*)(smem + LN_OFF + 5120);   // [8]

    auto ln_stats = [&](float ps1[4][4], float ps2[4][4], float invO) {
#pragma unroll
        for (int m = 1; m < 16; m <<= 1)
#pragma unroll
            for (int a = 0; a < 4; ++a)
#pragma unroll
                for (int r = 0; r < 4; ++r) {
                    ps1[a][r] += __shfl_xor(ps1[a][r], m);
                    ps2[a][r] += __shfl_xor(ps2[a][r], m);
                }
        if (lc == 0) {
#pragma unroll
            for (int a = 0; a < 4; ++a)
#pragma unroll
                for (int r = 0; r < 4; ++r) {
                    int row = wr * 64 + a * 16 + lg * 4 + r;
                    lnP[row * 4 + wc]       = ps1[a][r];
                    lnP[512 + row * 4 + wc] = ps2[a][r];
                }
        }
        __syncthreads();
        if (tid < 128) {
            float s1 = lnP[tid * 4] + lnP[tid * 4 + 1] + lnP[tid * 4 + 2] + lnP[tid * 4 + 3];
            float s2 = lnP[512 + tid * 4] + lnP[512 + tid * 4 + 1] +
                       lnP[512 + tid * 4 + 2] + lnP[512 + tid * 4 + 3];
            float mu = s1 * invO;
            float var = fmaxf(s2 * invO - mu * mu, 0.f);
            lnMR[tid]       = mu;
            lnMR[128 + tid] = rsqrtf(var + EPS_LN);
        }
        __syncthreads();
    };

    // ================= G1: actP(512) -> h2(264/288), LN(g2,b2), mish =================
    {
        constexpr int NT = 6;                      // BN 384
        f32x4 acc[4][NT];
#pragma unroll
        for (int a = 0; a < 4; ++a)
#pragma unroll
            for (int c = 0; c < NT; ++c) acc[a][c] = (f32x4){0.f, 0.f, 0.f, 0.f};

        auto stage1 = [&](int t, int b) {
#pragma unroll
            for (int i = 0; i < 4; ++i) {
                int c = wu + 8 * i;                // 0..31
                if (c < 24) {
                    const char* g = (const char*)W2p +
                        ((size_t)(c * 16) * 512) * 2 + (size_t)t * 64 + vofW2;
                    glds16(g, smem + (16384 + b * 24576 + c * 1024));
                } else {
                    int ca = c - 24;
                    const char* g = (const char*)actP +
                        ((size_t)(row0 + ca * 16) * 512) * 2 + (size_t)t * 64 + vofA;
                    glds16(g, smem + (b * 8192 + ca * 1024));
                }
            }
        };

        stage1(0, 0);
        __syncthreads();
        for (int t = 0; t < 16; ++t) {
            const int bsel = t & 1;
            if (t + 1 < 16) stage1(t + 1, bsel ^ 1);
            const char* Ab = smem + bsel * 8192 + (wr * 64 + lc) * 64 + fswz;
            const char* Bb = smem + 16384 + bsel * 24576 + (wc * 96 + lc) * 64 + fswz;
            bf16x8 afr[4], bfr[NT];
#pragma unroll
            for (int a = 0; a < 4; ++a) afr[a] = *(const bf16x8*)(Ab + a * 1024);
#pragma unroll
            for (int c = 0; c < NT; ++c) bfr[c] = *(const bf16x8*)(Bb + c * 1024);
            __builtin_amdgcn_s_setprio(1);
#pragma unroll
            for (int c = 0; c < NT; ++c)
#pragma unroll
                for (int a = 0; a < 4; ++a)
                    acc[a][c] = __builtin_amdgcn_mfma_f32_16x16x32_bf16(afr[a], bfr[c], acc[a][c], 0, 0, 0);
            __builtin_amdgcn_s_setprio(0);
            __syncthreads();
        }

        float ps1[4][4], ps2[4][4];
#pragma unroll
        for (int a = 0; a < 4; ++a)
#pragma unroll
            for (int r = 0; r < 4; ++r) { ps1[a][r] = 0.f; ps2[a][r] = 0.f; }
#pragma unroll
        for (int a = 0; a < 4; ++a)
#pragma unroll
            for (int c = 0; c < NT; ++c)
#pragma unroll
                for (int r = 0; r < 4; ++r) {
                    float v = acc[a][c][r];
                    ps1[a][r] += v;
                    ps2[a][r] = __fmaf_rn(v, v, ps2[a][r]);
                }
        ln_stats(ps1, ps2, 1.f / 264);

        float gcol[NT], bcol[NT];
#pragma unroll
        for (int c = 0; c < NT; ++c) {
            int col = wc * 96 + c * 16 + lc;
            gcol[c] = (col < 264) ? g2[col] : 0.f;
            bcol[c] = (col < 264) ? b2[col] : 0.f;
        }
#pragma unroll
        for (int a = 0; a < 4; ++a)
#pragma unroll
            for (int r = 0; r < 4; ++r) {
                int rl = wr * 64 + a * 16 + lg * 4 + r;
                float mu = lnMR[rl], rs = lnMR[128 + rl];
                int sx = (rl >> 1) & 3;
                int rowb = H2_OFF + rl * 576;
#pragma unroll
                for (int c = 0; c < NT; ++c) {
                    int col = wc * 96 + c * 16 + lc;
                    if (col < 288) {
                        unsigned short outv = 0;
                        if (col < 264) {
                            float v = (acc[a][c][r] - mu) * rs * gcol[c] + bcol[c];
                            outv = f2bf(mish_f(v));
                        }
                        int byte = rowb + ((col >> 5) << 6) +
                                   ((((col >> 3) & 3) ^ sx) << 4) + ((col & 7) << 1);
                        *(unsigned short*)(smem + byte) = outv;
                    }
                }
            }
        __syncthreads();
    }

    // ================= G2: h2(288) -> h3(128), +b3, LN(gh,bh), mish, |.| =================
    {
        constexpr int NT = 2;                      // BN 128
        f32x4 acc[4][NT];
#pragma unroll
        for (int a = 0; a < 4; ++a)
#pragma unroll
            for (int c = 0; c < NT; ++c) acc[a][c] = (f32x4){0.f, 0.f, 0.f, 0.f};

        auto stage2 = [&](int t, int b) {
            int c = wu;                            // 8 chunks, 1/wave
            const char* g = (const char*)W3p +
                ((size_t)(c * 16) * 288) * 2 + (size_t)t * 64 + vofW3;
            glds16(g, smem + (b * 8192 + c * 1024));
        };

        stage2(0, 0);
        __syncthreads();
        for (int t = 0; t < 9; ++t) {
            const int bsel = t & 1;
            if (t + 1 < 9) stage2(t + 1, bsel ^ 1);
            const char* Ab = smem + H2_OFF + (wr * 64 + lc) * 576 + t * 64 + fswz;
            const char* Bb = smem + bsel * 8192 + (wc * 32 + lc) * 64 + fswz;
            bf16x8 afr[4], bfr[NT];
#pragma unroll
            for (int a = 0; a < 4; ++a) afr[a] = *(const bf16x8*)(Ab + a * 16 * 576);
#pragma unroll
            for (int c = 0; c < NT; ++c) bfr[c] = *(const bf16x8*)(Bb + c * 1024);
            __builtin_amdgcn_s_setprio(1);
#pragma unroll
            for (int c = 0; c < NT; ++c)
#pragma unroll
                for (int a = 0; a < 4; ++a)
                    acc[a][c] = __builtin_amdgcn_mfma_f32_16x16x32_bf16(afr[a], bfr[c], acc[a][c], 0, 0, 0);
            __builtin_amdgcn_s_setprio(0);
            __syncthreads();
        }

#pragma unroll
        for (int c = 0; c < NT; ++c) {
            int col = wc * 32 + c * 16 + lc;
            float bv = b3[col];
#pragma unroll
            for (int a = 0; a < 4; ++a)
#pragma unroll
                for (int r = 0; r < 4; ++r) acc[a][c][r] += bv;
        }
        float ps1[4][4], ps2[4][4];
#pragma unroll
        for (int a = 0; a < 4; ++a)
#pragma unroll
            for (int r = 0; r < 4; ++r) { ps1[a][r] = 0.f; ps2[a][r] = 0.f; }
#pragma unroll
        for (int a = 0; a < 4; ++a)
#pragma unroll
            for (int c = 0; c < NT; ++c)
#pragma unroll
                for (int r = 0; r < 4; ++r) {
                    float v = acc[a][c][r];
                    ps1[a][r] += v;
                    ps2[a][r] = __fmaf_rn(v, v, ps2[a][r]);
                }
        ln_stats(ps1, ps2, 1.f / 128);

        float gcol[NT], bcol[NT];
#pragma unroll
        for (int c = 0; c < NT; ++c) {
            int col = wc * 32 + c * 16 + lc;
            gcol[c] = gh[col];
            bcol[c] = bh[col];
        }
        float asum = 0.f;
#pragma unroll
        for (int a = 0; a < 4; ++a)
#pragma unroll
            for (int r = 0; r < 4; ++r) {
                int rl = wr * 64 + a * 16 + lg * 4 + r;
                float mu = lnMR[rl], rs = lnMR[128 + rl];
                int sx = (rl >> 1) & 3;
                int rowb = H3_OFF + rl * 256;
#pragma unroll
                for (int c = 0; c < NT; ++c) {
                    int col = wc * 32 + c * 16 + lc;
                    float v = (acc[a][c][r] - mu) * rs * gcol[c] + bcol[c];
                    float mz = mish_f(v);
                    asum += fabsf(mz);
                    int byte = rowb + ((col >> 5) << 6) +
                               ((((col >> 3) & 3) ^ sx) << 4) + ((col & 7) << 1);
                    *(unsigned short*)(smem + byte) = f2bf(mz);
                }
            }
#pragma unroll
        for (int m = 1; m < 64; m <<= 1) asum += __shfl_xor(asum, m);
        if (lane == 0) wsum[wu] = asum;
        __syncthreads();
        if (tid == 0) {
            float s = 0.f;
            for (int w = 0; w < 8; ++w) s += wsum[w];
            partials[blockIdx.x] = s;
        }
        __syncthreads();
    }

    // ================= G3: h3(128) -> h4(264/288), LN(g3,b3n), mish =================
    {
        constexpr int NT = 6;                      // BN 384
        f32x4 acc[4][NT];
#pragma unroll
        for (int a = 0; a < 4; ++a)
#pragma unroll
            for (int c = 0; c < NT; ++c) acc[a][c] = (f32x4){0.f, 0.f, 0.f, 0.f};

        auto stage3 = [&](int t, int b) {
#pragma unroll
            for (int i = 0; i < 3; ++i) {
                int c = wu + 8 * i;                // 0..23
                const char* g = (const char*)D1p +
                    ((size_t)(c * 16) * 128) * 2 + (size_t)t * 64 + vofD1;
                glds16(g, smem + (b * 24576 + c * 1024));
            }
        };

        stage3(0, 0);
        __syncthreads();
        for (int t = 0; t < 4; ++t) {
            const int bsel = t & 1;
            if (t + 1 < 4) stage3(t + 1, bsel ^ 1);
            const char* Ab = smem + H3_OFF + (wr * 64 + lc) * 256 + t * 64 + fswz;
            const char* Bb = smem + bsel * 24576 + (wc * 96 + lc) * 64 + fswz;
            bf16x8 afr[4], bfr[NT];
#pragma unroll
            for (int a = 0; a < 4; ++a) afr[a] = *(const bf16x8*)(Ab + a * 16 * 256);
#pragma unroll
            for (int c = 0; c < NT; ++c) bfr[c] = *(const bf16x8*)(Bb + c * 1024);
            __builtin_amdgcn_s_setprio(1);
#pragma unroll
            for (int c = 0; c < NT; ++c)
#pragma unroll
                for (int a = 0; a < 4; ++a)
                    acc[a][c] = __builtin_amdgcn_mfma_f32_16x16x32_bf16(afr[a], bfr[c], acc[a][c], 0, 0, 0);
            __builtin_amdgcn_s_setprio(0);
            __syncthreads();
        }

        float ps1[4][4], ps2[4][4];
#pragma unroll
        for (int a = 0; a < 4; ++a)
#pragma unroll
            for (int r = 0; r < 4; ++r) { ps1[a][r] = 0.f; ps2[a][r] = 0.f; }
#pragma unroll
        for (int a = 0; a < 4; ++a)
#pragma unroll
            for (int c = 0; c < NT; ++c)
#pragma unroll
                for (int r = 0; r < 4; ++r) {
                    float v = acc[a][c][r];
                    ps1[a][r] += v;
                    ps2[a][r] = __fmaf_rn(v, v, ps2[a][r]);
                }
        ln_stats(ps1, ps2, 1.f / 264);

        float gcol[NT], bcol[NT];
#pragma unroll
        for (int c = 0; c < NT; ++c) {
            int col = wc * 96 + c * 16 + lc;
            gcol[c] = (col < 264) ? g3[col] : 0.f;
            bcol[c] = (col < 264) ? b3n[col] : 0.f;
        }
#pragma unroll
        for (int a = 0; a < 4; ++a)
#pragma unroll
            for (int r = 0; r < 4; ++r) {
                int rl = wr * 64 + a * 16 + lg * 4 + r;
                float mu = lnMR[rl], rs = lnMR[128 + rl];
                int sx = (rl >> 1) & 3;
                int rowb = H4_OFF + rl * 576;
#pragma unroll
                for (int c = 0; c < NT; ++c) {
                    int col = wc * 96 + c * 16 + lc;
                    if (col < 288) {
                        unsigned short outv = 0;
                        if (col < 264) {
                            float v = (acc[a][c][r] - mu) * rs * gcol[c] + bcol[c];
                            outv = f2bf(mish_f(v));
                        }
                        int byte = rowb + ((col >> 5) << 6) +
                                   ((((col >> 3) & 3) ^ sx) << 4) + ((col & 7) << 1);
                        *(unsigned short*)(smem + byte) = outv;
                    }
                }
            }
        __syncthreads();
    }

    // ================= G4: h4(288) -> actH(512), LN(g4,b4), mish =================
    {
        constexpr int NT = 8;                      // BN 512
        f32x4 acc[4][NT];
#pragma unroll
        for (int a = 0; a < 4; ++a)
#pragma unroll
            for (int c = 0; c < NT; ++c) acc[a][c] = (f32x4){0.f, 0.f, 0.f, 0.f};

        auto stage4 = [&](int t) {                 // single-buffered W5 (32K)
#pragma unroll
            for (int i = 0; i < 4; ++i) {
                int c = wu + 8 * i;                // 0..31
                const char* g = (const char*)D2p +
                    ((size_t)(c * 16) * 320) * 2 + (size_t)t * 64 + vofW5;
                glds16(g, smem + (W5_OFF + c * 1024));
            }
        };

        for (int t = 0; t < 9; ++t) {
            stage4(t);
            __syncthreads();                       // drains vmcnt before reads
            const char* Ab = smem + H4_OFF + (wr * 64 + lc) * 576 + t * 64 + fswz;
            const char* Bb = smem + W5_OFF + (wc * 128 + lc) * 64 + fswz;
            bf16x8 afr[4], bfr[NT];
#pragma unroll
            for (int a = 0; a < 4; ++a) afr[a] = *(const bf16x8*)(Ab + a * 16 * 576);
#pragma unroll
            for (int c = 0; c < NT; ++c) bfr[c] = *(const bf16x8*)(Bb + c * 1024);
            __builtin_amdgcn_s_setprio(1);
#pragma unroll
            for (int c = 0; c < NT; ++c)
#pragma unroll
                for (int a = 0; a < 4; ++a)
                    acc[a][c] = __builtin_amdgcn_mfma_f32_16x16x32_bf16(afr[a], bfr[c], acc[a][c], 0, 0, 0);
            __builtin_amdgcn_s_setprio(0);
            __syncthreads();                       // reads done before next stage
        }

        float ps1[4][4], ps2[4][4];
#pragma unroll
        for (int a = 0; a < 4; ++a)
#pragma unroll
            for (int r = 0; r < 4; ++r) { ps1[a][r] = 0.f; ps2[a][r] = 0.f; }
#pragma unroll
        for (int a = 0; a < 4; ++a)
#pragma unroll
            for (int c = 0; c < NT; ++c)
#pragma unroll
                for (int r = 0; r < 4; ++r) {
                    float v = acc[a][c][r];
                    ps1[a][r] += v;
                    ps2[a][r] = __fmaf_rn(v, v, ps2[a][r]);
                }
        ln_stats(ps1, ps2, 1.f / 512);

        float gcol[NT], bcol[NT];
#pragma unroll
        for (int c = 0; c < NT; ++c) {
            int col = wc * 128 + c * 16 + lc;
            gcol[c] = g4[col];
            bcol[c] = b4[col];
        }
#pragma unroll
        for (int a = 0; a < 4; ++a)
#pragma unroll
            for (int r = 0; r < 4; ++r) {
                int rl = wr * 64 + a * 16 + lg * 4 + r;
                float mu = lnMR[rl], rs = lnMR[128 + rl];
                size_t rowoff = (size_t)(row0 + rl) * 512;
#pragma unroll
                for (int c = 0; c < NT; ++c) {
                    int col = wc * 128 + c * 16 + lc;
                    float v = (acc[a][c][r] - mu) * rs * gcol[c] + bcol[c];
                    actH[rowoff + col] = f2bf(mish_f(v));
                }
            }
    }
}

// ---------------- L6 single-pass: 512 -> 784(896), +bo, sigmoid ----------------
// Block 512 thr = 8 waves (2x4), 128-row tile, BK=32, LDS 128K.
__global__ __launch_bounds__(512, 2)
void layer_out(const unsigned short* __restrict__ actH,  // [B][512]
               const unsigned short* __restrict__ D3p,   // [896][512]
               const float* __restrict__ bo,
               float* __restrict__ Out)                  // [B][784]
{
    constexpr int NT = 14, NCHW = 56, NCH = 64, MAXC = 8;
    constexpr int ABY = 8192, WBY = 57344;
    __shared__ __align__(16) char smem[2 * ABY + 2 * WBY];

    const int tid  = threadIdx.x;
    const int lane = tid & 63;
    const int wu   = __builtin_amdgcn_readfirstlane(tid >> 6);
    const int wr = wu >> 2, wc = wu & 3;
    const int lg = lane >> 4, lc = lane & 15;
    const int row0 = blockIdx.x * 128;

    const int sgl = (lane & 3) ^ ((lane >> 3) & 3);
    const size_t vof = ((size_t)(lane >> 2) * 512 + (size_t)(sgl << 3)) * 2;

    auto stage = [&](int t, int b) {
#pragma unroll
        for (int i = 0; i < MAXC; ++i) {
            int c = wu + 8 * i;                    // 0..63
            if (c < NCHW) {
                const char* g = (const char*)D3p +
                    ((size_t)(c * 16) * 512) * 2 + (size_t)t * 64 + vof;
                glds16(g, smem + (2 * ABY + b * WBY + c * 1024));
            } else {
                int ca = c - NCHW;
                const char* g = (const char*)actH +
                    ((size_t)(row0 + ca * 16) * 512) * 2 + (size_t)t * 64 + vof;
                glds16(g, smem + (b * ABY + ca * 1024));
            }
        }
    };

    stage(0, 0);
    __syncthreads();

    f32x4 acc[4][NT];
#pragma unroll
    for (int a = 0; a < 4; ++a)
#pragma unroll
        for (int c = 0; c < NT; ++c) acc[a][c] = (f32x4){0.f, 0.f, 0.f, 0.f};

    const int fswz = ((lg ^ ((lc >> 1) & 3)) << 4);

    for (int t = 0; t < 16; ++t) {
        const int bsel = t & 1;
        if (t + 1 < 16) stage(t + 1, bsel ^ 1);
        const char* Ab = smem + bsel * ABY + (wr * 64 + lc) * 64 + fswz;
        const char* Bb = smem + 2 * ABY + bsel * WBY + (wc * 224 + lc) * 64 + fswz;
        bf16x8 afr[4], bfr[NT];
#pragma unroll
        for (int a = 0; a < 4; ++a) afr[a] = *(const bf16x8*)(Ab + a * 1024);
#pragma unroll
        for (int c = 0; c < NT; ++c) bfr[c] = *(const bf16x8*)(Bb + c * 1024);
        __builtin_amdgcn_s_setprio(1);
#pragma unroll
        for (int c = 0; c < NT; ++c)
#pragma unroll
            for (int a = 0; a < 4; ++a)
                acc[a][c] = __builtin_amdgcn_mfma_f32_16x16x32_bf16(afr[a], bfr[c], acc[a][c], 0, 0, 0);
        __builtin_amdgcn_s_setprio(0);
        __syncthreads();
    }

#pragma unroll
    for (int c = 0; c < NT; ++c) {
        int col = wc * 224 + c * 16 + lc;
        bool ok = col < 784;
        float bv = ok ? bo[col] : 0.f;
#pragma unroll
        for (int a = 0; a < 4; ++a)
#pragma unroll
            for (int r = 0; r < 4; ++r) {
                if (ok) {
                    int rl = wr * 64 + a * 16 + lg * 4 + r;
                    float v = acc[a][c][r] + bv;
                    Out[(size_t)(row0 + rl) * 784 + col] = 1.f / (1.f + __expf(-v));
                }
            }
    }
}

// ---------------- deterministic reduction of |latent| partials ----------------
__global__ void reduce_abs(const float* __restrict__ partials, float* __restrict__ out) {
    __shared__ float sm[256];
    float s = 0.f;
    for (int i = threadIdx.x; i < 512; i += 256) s += partials[i];  // fixed order
    sm[threadIdx.x] = s;
    __syncthreads();
    for (int step = 128; step > 0; step >>= 1) {
        if (threadIdx.x < step) sm[threadIdx.x] += sm[threadIdx.x + step];
        __syncthreads();
    }
    if (threadIdx.x == 0) out[0] = sm[0];
}

extern "C" void kernel_launch(void* const* d_in, const int* in_sizes, int n_in,
                              void* d_out, int out_size, void* d_ws, size_t ws_size,
                              hipStream_t stream)
{
    const float* x   = (const float*)d_in[0];
    const float* W1  = (const float*)d_in[1];
    const float* g1  = (const float*)d_in[2];
    const float* b1  = (const float*)d_in[3];
    const float* W2  = (const float*)d_in[4];
    const float* g2  = (const float*)d_in[5];
    const float* b2  = (const float*)d_in[6];
    const float* W3  = (const float*)d_in[7];
    const float* b3  = (const float*)d_in[8];
    const float* gh  = (const float*)d_in[9];
    const float* bh  = (const float*)d_in[10];
    const float* D1  = (const float*)d_in[11];
    const float* g3  = (const float*)d_in[12];
    const float* b3n = (const float*)d_in[13];
    const float* D2  = (const float*)d_in[14];
    const float* g4  = (const float*)d_in[15];
    const float* b4  = (const float*)d_in[16];
    const float* D3  = (const float*)d_in[17];
    const float* bo  = (const float*)d_in[18];

    char* ws = (char*)d_ws;
    size_t off = 0;
    auto alloc = [&](size_t bytes) -> char* {
        char* p = ws + off;
        off += (bytes + 255) & ~(size_t)255;
        return p;
    };
    unsigned short* W1p = (unsigned short*)alloc((size_t)512 * 832 * 2);
    unsigned short* W2p = (unsigned short*)alloc((size_t)384 * 512 * 2);
    unsigned short* W3p = (unsigned short*)alloc((size_t)128 * 288 * 2);
    unsigned short* D1p = (unsigned short*)alloc((size_t)384 * 128 * 2);
    unsigned short* D2p = (unsigned short*)alloc((size_t)512 * 320 * 2);
    unsigned short* D3p = (unsigned short*)alloc((size_t)896 * 512 * 2);
    unsigned short* actP = (unsigned short*)alloc((size_t)B_ROWS * 512 * 2);
    unsigned short* actH = (unsigned short*)alloc((size_t)B_ROWS * 512 * 2);
    float* partials = (float*)alloc(512 * 4);

    CvtArgs ca;
    ca.src[0] = W1; ca.dst[0] = W1p; ca.O[0] = 512; ca.K[0] = 784; ca.KP[0] = 832;
    ca.src[1] = W2; ca.dst[1] = W2p; ca.O[1] = 264; ca.K[1] = 512; ca.KP[1] = 512;
    ca.src[2] = W3; ca.dst[2] = W3p; ca.O[2] = 128; ca.K[2] = 264; ca.KP[2] = 288;
    ca.src[3] = D1; ca.dst[3] = D1p; ca.O[3] = 264; ca.K[3] = 128; ca.KP[3] = 128;
    ca.src[4] = D2; ca.dst[4] = D2p; ca.O[4] = 512; ca.K[4] = 264; ca.KP[4] = 320;
    ca.src[5] = D3; ca.dst[5] = D3p; ca.O[5] = 784; ca.K[5] = 512; ca.KP[5] = 512;
    ca.base[0] = 0;    ca.base[1] = 512;  ca.base[2] = 896;
    ca.base[3] = 1024; ca.base[4] = 1408; ca.base[5] = 1920; ca.base[6] = 2816;
    wpad_kernel<<<2816, 256, 0, stream>>>(ca);

    const int NB = B_ROWS / 128;  // 512 row-tiles

    // L1: x[.,784] @ W1^T -> 512, LN, mish   (v9, LDS 160K)
    layer9<832, 784, 512, 512, 512, 13, true,  false, false, true>
        <<<NB, 512, 0, stream>>>(x, W1p, g1, b1, nullptr, actP, nullptr);
    // L2..L5 fused: actP -> (LDS h2 -> h3 -> h4) -> actH + |latent| partials
    quad<<<NB, 512, 0, stream>>>(actP, W2p, W3p, D1p, D2p,
                                 g2, b2, gh, bh, b3, g3, b3n, g4, b4,
                                 actH, partials);
    // L6: single-pass 512 -> 784(896), +bo, sigmoid
    layer_out<<<NB, 512, 0, stream>>>(actH, D3p, bo, (float*)d_out);

    reduce_abs<<<1, 256, 0, stream>>>(partials, (float*)d_out + (size_t)B_ROWS * 784);
}

// Round 15
// 435.334 us; speedup vs baseline: 1.4898x; 1.4898x over previous
//
#include <hip/hip_runtime.h>

// AutoEncoder v15, bf16 MFMA (gfx950).
// L1: v9 kernel. L2+L3+L4+L5 fused into `quad` (h2/h3/h4 in LDS).
// L6: v13's two-pass BN=448 layer9 (no spill). Best-of-rounds assembly.

typedef short bf16x8 __attribute__((ext_vector_type(8)));
typedef float f32x4  __attribute__((ext_vector_type(4)));

#define B_ROWS 65536
#define EPS_LN 1e-5f

static __device__ __forceinline__ unsigned short f2bf(float f) {
    union { float f; unsigned u; } v; v.f = f;
    unsigned r = v.u + 0x7FFFu + ((v.u >> 16) & 1u);   // RNE
    return (unsigned short)(r >> 16);
}

static __device__ __forceinline__ float mish_f(float x) {
    if (x > 15.f) return x;
    float u = __expf(x);
    float p = __fmaf_rn(u, u, 2.f * u);
    return x * (p / (p + 2.f));
}

// direct global->LDS, 16B per lane; LDS base must be wave-uniform
static __device__ __forceinline__ void glds16(const void* g, void* l) {
    typedef __attribute__((address_space(3))) unsigned lds_u32;
    typedef __attribute__((address_space(1))) const unsigned glb_u32;
    lds_u32* lp = (lds_u32*)l;
    unsigned lofs = __builtin_amdgcn_readfirstlane((unsigned)(unsigned long long)lp);
    lp = (lds_u32*)(unsigned long long)lofs;
    __builtin_amdgcn_global_load_lds((glb_u32*)g, lp, 16, 0, 0);
}

// ---------------- padded weight fp32->bf16 conversion ----------------
struct CvtArgs {
    const float* src[6];
    unsigned short* dst[6];
    int O[6], K[6], KP[6];
    int base[7];
};

__global__ void wpad_kernel(CvtArgs a) {
    int b = blockIdx.x;
    int seg = 0;
    while (b >= a.base[seg + 1]) ++seg;
    int r = b - a.base[seg];
    int O = a.O[seg], K = a.K[seg], KP = a.KP[seg];
    const float* s = a.src[seg];
    unsigned short* d = a.dst[seg];
    for (int c = threadIdx.x; c < KP; c += 256) {
        unsigned short v = 0;
        if (r < O && c < K) v = f2bf(s[(size_t)r * K + c]);
        d[(size_t)r * KP + c] = v;
    }
}

// ---------------- v9 fused layer kernel (BK=64) — L1 and L6 ----------------
template<int KP, int ASTR, int BN, int OREAL, int OSTRIDE, int NKT,
         bool SRCF32, bool HASBIAS, bool ABS, bool LN>
__global__ __launch_bounds__(512, 2)
void layer9(const void* __restrict__ Asrc,
            const unsigned short* __restrict__ Wp,
            const float* __restrict__ gam,
            const float* __restrict__ bet,
            const float* __restrict__ bias,
            void* __restrict__ Aout,
            float* __restrict__ partials)
{
    constexpr int NT   = BN / 64;
    constexpr int NCHW = BN / 8;
    constexpr int NCH  = NCHW + (SRCF32 ? 0 : 16);
    constexpr int MAXC = (NCH + 7) / 8;
    constexpr int ABY  = 128 * 128;
    constexpr int WBY  = BN * 128;

    __shared__ __align__(16) char smem[2 * ABY + 2 * WBY];

    const int tid  = threadIdx.x;
    const int lane = tid & 63;
    const int wu   = __builtin_amdgcn_readfirstlane(tid >> 6);
    const int wr = wu >> 2, wc = wu & 3;
    const int lg = lane >> 4, lc = lane & 15;
    const int row0  = blockIdx.x * 128;
    const int cbase = LN ? 0 : blockIdx.y * BN;

    const int crow = lane >> 3;
    const int sg   = (lane & 7) ^ crow;
    const size_t vofW = ((size_t)crow * KP + (size_t)(sg << 3)) * 2;
    const size_t vofA = ((size_t)crow * ASTR + (size_t)(sg << 3)) * 2;

    auto stage = [&](int t, int b) {
#pragma unroll
        for (int i = 0; i < MAXC; ++i) {
            int c = wu + 8 * i;
            if (c < NCHW) {
                const char* g = (const char*)Wp +
                    ((size_t)(cbase + c * 8) * KP) * 2 + (size_t)t * 128 + vofW;
                glds16(g, smem + (2 * ABY + b * WBY + c * 1024));
            } else if (c < NCH) {
                int ca = c - NCHW;
                const char* g = (const char*)Asrc +
                    ((size_t)(row0 + ca * 8) * ASTR) * 2 + (size_t)t * 128 + vofA;
                glds16(g, smem + (b * ABY + ca * 1024));
            }
        }
    };

    const int ar = tid >> 2, as = tid & 3;
    const float* axp = (const float*)Asrc + (size_t)(row0 + ar) * ASTR + as * 16;
    float4 rA[4];
#pragma unroll
    for (int j = 0; j < 4; ++j) rA[j] = make_float4(0, 0, 0, 0);

    auto loadA1 = [&](int t) {
#pragma unroll
        for (int j = 0; j < 4; ++j) {
            int c0 = t * 64 + as * 16 + j * 4;
            rA[j] = (c0 + 3 < 784) ? *(const float4*)(axp + t * 64 + j * 4)
                                   : make_float4(0, 0, 0, 0);
        }
    };
    auto pubA = [&](int b) {
        union { unsigned short us[8]; uint4 v; } u0, u1;
        u0.us[0] = f2bf(rA[0].x); u0.us[1] = f2bf(rA[0].y);
        u0.us[2] = f2bf(rA[0].z); u0.us[3] = f2bf(rA[0].w);
        u0.us[4] = f2bf(rA[1].x); u0.us[5] = f2bf(rA[1].y);
        u0.us[6] = f2bf(rA[1].z); u0.us[7] = f2bf(rA[1].w);
        u1.us[0] = f2bf(rA[2].x); u1.us[1] = f2bf(rA[2].y);
        u1.us[2] = f2bf(rA[2].z); u1.us[3] = f2bf(rA[2].w);
        u1.us[4] = f2bf(rA[3].x); u1.us[5] = f2bf(rA[3].y);
        u1.us[6] = f2bf(rA[3].z); u1.us[7] = f2bf(rA[3].w);
        int s0 = as * 2, rb = b * ABY + ar * 128, rx = ar & 7;
        *(uint4*)(smem + rb + (((s0    ) ^ rx) << 4)) = u0.v;
        *(uint4*)(smem + rb + (((s0 + 1) ^ rx) << 4)) = u1.v;
    };

    stage(0, 0);
    if constexpr (SRCF32) { loadA1(0); pubA(0); }
    __syncthreads();

    f32x4 acc[4][NT];
#pragma unroll
    for (int a = 0; a < 4; ++a)
#pragma unroll
        for (int c = 0; c < NT; ++c) acc[a][c] = (f32x4){0.f, 0.f, 0.f, 0.f};

    const int f0 = ((lg ^ (lc & 7)) << 4);

    for (int t = 0; t < NKT; ++t) {
        const int bsel = t & 1;
        if (t + 1 < NKT) {
            stage(t + 1, bsel ^ 1);
            if constexpr (SRCF32) loadA1(t + 1);
        }
        const char* Ab = smem + bsel * ABY + (wr * 64 + lc) * 128;
        const char* Bb = smem + 2 * ABY + bsel * WBY + (wc * NT * 16 + lc) * 128;
#pragma unroll
        for (int h = 0; h < 2; ++h) {
            const int fh = f0 ^ (h << 6);
            bf16x8 afr[4], bfr[NT];
#pragma unroll
            for (int a = 0; a < 4; ++a)
                afr[a] = *(const bf16x8*)(Ab + a * 2048 + fh);
#pragma unroll
            for (int c = 0; c < NT; ++c)
                bfr[c] = *(const bf16x8*)(Bb + c * 2048 + fh);
            __builtin_amdgcn_s_setprio(1);
#pragma unroll
            for (int c = 0; c < NT; ++c)
#pragma unroll
                for (int a = 0; a < 4; ++a)
                    acc[a][c] = __builtin_amdgcn_mfma_f32_16x16x32_bf16(afr[a], bfr[c], acc[a][c], 0, 0, 0);
            __builtin_amdgcn_s_setprio(0);
        }
        if constexpr (SRCF32) { if (t + 1 < NKT) pubA(bsel ^ 1); }
        __syncthreads();
    }

    if constexpr (LN) {
        if constexpr (HASBIAS) {
#pragma unroll
            for (int c = 0; c < NT; ++c) {
                int col = wc * NT * 16 + c * 16 + lc;
                float bv = (col < OREAL) ? bias[col] : 0.f;
#pragma unroll
                for (int a = 0; a < 4; ++a)
#pragma unroll
                    for (int r = 0; r < 4; ++r) acc[a][c][r] += bv;
            }
        }
        float ps1[4][4], ps2[4][4];
#pragma unroll
        for (int a = 0; a < 4; ++a)
#pragma unroll
            for (int r = 0; r < 4; ++r) { ps1[a][r] = 0.f; ps2[a][r] = 0.f; }
#pragma unroll
        for (int a = 0; a < 4; ++a)
#pragma unroll
            for (int c = 0; c < NT; ++c)
#pragma unroll
                for (int r = 0; r < 4; ++r) {
                    float v = acc[a][c][r];
                    ps1[a][r] += v;
                    ps2[a][r] = __fmaf_rn(v, v, ps2[a][r]);
                }
#pragma unroll
        for (int m = 1; m < 16; m <<= 1)
#pragma unroll
            for (int a = 0; a < 4; ++a)
#pragma unroll
                for (int r = 0; r < 4; ++r) {
                    ps1[a][r] += __shfl_xor(ps1[a][r], m);
                    ps2[a][r] += __shfl_xor(ps2[a][r], m);
                }

        float* lnP  = (float*)smem;
        float* lnMR = (float*)(smem + 4096);
        float* wsum = (float*)(smem + 5120);

        if (lc == 0) {
#pragma unroll
            for (int a = 0; a < 4; ++a)
#pragma unroll
                for (int r = 0; r < 4; ++r) {
                    int row = wr * 64 + a * 16 + lg * 4 + r;
                    lnP[row * 4 + wc]       = ps1[a][r];
                    lnP[512 + row * 4 + wc] = ps2[a][r];
                }
        }
        __syncthreads();
        if (tid < 128) {
            float s1 = lnP[tid * 4] + lnP[tid * 4 + 1] + lnP[tid * 4 + 2] + lnP[tid * 4 + 3];
            float s2 = lnP[512 + tid * 4] + lnP[512 + tid * 4 + 1] +
                       lnP[512 + tid * 4 + 2] + lnP[512 + tid * 4 + 3];
            float mu = s1 * (1.f / OREAL);
            float var = fmaxf(s2 * (1.f / OREAL) - mu * mu, 0.f);
            lnMR[tid]       = mu;
            lnMR[128 + tid] = rsqrtf(var + EPS_LN);
        }
        __syncthreads();

        float gcol[NT], bcol[NT];
#pragma unroll
        for (int c = 0; c < NT; ++c) {
            int col = wc * NT * 16 + c * 16 + lc;
            gcol[c] = (col < OREAL) ? gam[col] : 0.f;
            bcol[c] = (col < OREAL) ? bet[col] : 0.f;
        }

        float asum = 0.f;
        unsigned short* outp = (unsigned short*)Aout;
#pragma unroll
        for (int a = 0; a < 4; ++a)
#pragma unroll
            for (int r = 0; r < 4; ++r) {
                int rl = wr * 64 + a * 16 + lg * 4 + r;
                float mu = lnMR[rl], rs = lnMR[128 + rl];
                size_t rowoff = (size_t)(row0 + rl) * OSTRIDE;
#pragma unroll
                for (int c = 0; c < NT; ++c) {
                    int col = wc * NT * 16 + c * 16 + lc;
                    if (col < OSTRIDE) {
                        unsigned short outv = 0;
                        if (col < OREAL) {
                            float v = (acc[a][c][r] - mu) * rs * gcol[c] + bcol[c];
                            float mz = mish_f(v);
                            if (ABS) asum += fabsf(mz);
                            outv = f2bf(mz);
                        }
                        outp[rowoff + col] = outv;
                    }
                }
            }

        if constexpr (ABS) {
#pragma unroll
            for (int m = 1; m < 64; m <<= 1) asum += __shfl_xor(asum, m);
            if (lane == 0) wsum[wu] = asum;
            __syncthreads();
            if (tid == 0) {
                float s = 0.f;
                for (int w = 0; w < 8; ++w) s += wsum[w];
                partials[blockIdx.x] = s;
            }
        }
    } else {
        float* outp = (float*)Aout;
#pragma unroll
        for (int c = 0; c < NT; ++c) {
            int col = cbase + wc * NT * 16 + c * 16 + lc;
            bool ok = col < OREAL;
            float bv = ok ? bias[col] : 0.f;
#pragma unroll
            for (int a = 0; a < 4; ++a)
#pragma unroll
                for (int r = 0; r < 4; ++r) {
                    if (ok) {
                        int rl = wr * 64 + a * 16 + lg * 4 + r;
                        float v = acc[a][c][r] + bv;
                        outp[(size_t)(row0 + rl) * OSTRIDE + col] = 1.f / (1.f + __expf(-v));
                    }
                }
        }
    }
}

// ---------------- quad kernel: L2+L3+L4+L5 fused, activations in LDS ----------------
#define H2_OFF  65536
#define H3_OFF  122880
#define H4_OFF  49152
#define W5_OFF  122880
#define LN_OFF  155648

__global__ __launch_bounds__(512, 2)
void quad(const unsigned short* __restrict__ actP,
          const unsigned short* __restrict__ W2p,   // [384][512]
          const unsigned short* __restrict__ W3p,   // [128][288]
          const unsigned short* __restrict__ D1p,   // [384][128]
          const unsigned short* __restrict__ D2p,   // [512][320]
          const float* __restrict__ g2, const float* __restrict__ b2,
          const float* __restrict__ gh, const float* __restrict__ bh,
          const float* __restrict__ b3,
          const float* __restrict__ g3, const float* __restrict__ b3n,
          const float* __restrict__ g4, const float* __restrict__ b4,
          unsigned short* __restrict__ actH,        // [B][512]
          float* __restrict__ partials)
{
    __shared__ __align__(16) char smem[160800];

    const int tid  = threadIdx.x;
    const int lane = tid & 63;
    const int wu   = __builtin_amdgcn_readfirstlane(tid >> 6);
    const int wr = wu >> 2, wc = wu & 3;
    const int lg = lane >> 4, lc = lane & 15;
    const int row0 = blockIdx.x * 128;

    const int sgl = (lane & 3) ^ ((lane >> 3) & 3);
    const size_t vofA  = ((size_t)(lane >> 2) * 512 + (size_t)(sgl << 3)) * 2;
    const size_t vofW2 = vofA;
    const size_t vofW3 = ((size_t)(lane >> 2) * 288 + (size_t)(sgl << 3)) * 2;
    const size_t vofD1 = ((size_t)(lane >> 2) * 128 + (size_t)(sgl << 3)) * 2;
    const size_t vofW5 = ((size_t)(lane >> 2) * 320 + (size_t)(sgl << 3)) * 2;

    const int fswz = ((lg ^ ((lc >> 1) & 3)) << 4);

    float* lnP  = (float*)(smem + LN_OFF);
    float* lnMR = (float*)(smem + LN_OFF + 4096);
    float* wsum = (float*)(smem + LN_OFF + 5120);

    auto ln_stats = [&](float ps1[4][4], float ps2[4][4], float invO) {
#pragma unroll
        for (int m = 1; m < 16; m <<= 1)
#pragma unroll
            for (int a = 0; a < 4; ++a)
#pragma unroll
                for (int r = 0; r < 4; ++r) {
                    ps1[a][r] += __shfl_xor(ps1[a][r], m);
                    ps2[a][r] += __shfl_xor(ps2[a][r], m);
                }
        if (lc == 0) {
#pragma unroll
            for (int a = 0; a < 4; ++a)
#pragma unroll
                for (int r = 0; r < 4; ++r) {
                    int row = wr * 64 + a * 16 + lg * 4 + r;
                    lnP[row * 4 + wc]       = ps1[a][r];
                    lnP[512 + row * 4 + wc] = ps2[a][r];
                }
        }
        __syncthreads();
        if (tid < 128) {
            float s1 = lnP[tid * 4] + lnP[tid * 4 + 1] + lnP[tid * 4 + 2] + lnP[tid * 4 + 3];
            float s2 = lnP[512 + tid * 4] + lnP[512 + tid * 4 + 1] +
                       lnP[512 + tid * 4 + 2] + lnP[512 + tid * 4 + 3];
            float mu = s1 * invO;
            float var = fmaxf(s2 * invO - mu * mu, 0.f);
            lnMR[tid]       = mu;
            lnMR[128 + tid] = rsqrtf(var + EPS_LN);
        }
        __syncthreads();
    };

    // ================= G1: actP(512) -> h2(264/288), LN(g2,b2), mish =================
    {
        constexpr int NT = 6;
        f32x4 acc[4][NT];
#pragma unroll
        for (int a = 0; a < 4; ++a)
#pragma unroll
            for (int c = 0; c < NT; ++c) acc[a][c] = (f32x4){0.f, 0.f, 0.f, 0.f};

        auto stage1 = [&](int t, int b) {
#pragma unroll
            for (int i = 0; i < 4; ++i) {
                int c = wu + 8 * i;
                if (c < 24) {
                    const char* g = (const char*)W2p +
                        ((size_t)(c * 16) * 512) * 2 + (size_t)t * 64 + vofW2;
                    glds16(g, smem + (16384 + b * 24576 + c * 1024));
                } else {
                    int ca = c - 24;
                    const char* g = (const char*)actP +
                        ((size_t)(row0 + ca * 16) * 512) * 2 + (size_t)t * 64 + vofA;
                    glds16(g, smem + (b * 8192 + ca * 1024));
                }
            }
        };

        stage1(0, 0);
        __syncthreads();
        for (int t = 0; t < 16; ++t) {
            const int bsel = t & 1;
            if (t + 1 < 16) stage1(t + 1, bsel ^ 1);
            const char* Ab = smem + bsel * 8192 + (wr * 64 + lc) * 64 + fswz;
            const char* Bb = smem + 16384 + bsel * 24576 + (wc * 96 + lc) * 64 + fswz;
            bf16x8 afr[4], bfr[NT];
#pragma unroll
            for (int a = 0; a < 4; ++a) afr[a] = *(const bf16x8*)(Ab + a * 1024);
#pragma unroll
            for (int c = 0; c < NT; ++c) bfr[c] = *(const bf16x8*)(Bb + c * 1024);
            __builtin_amdgcn_s_setprio(1);
#pragma unroll
            for (int c = 0; c < NT; ++c)
#pragma unroll
                for (int a = 0; a < 4; ++a)
                    acc[a][c] = __builtin_amdgcn_mfma_f32_16x16x32_bf16(afr[a], bfr[c], acc[a][c], 0, 0, 0);
            __builtin_amdgcn_s_setprio(0);
            __syncthreads();
        }

        float ps1[4][4], ps2[4][4];
#pragma unroll
        for (int a = 0; a < 4; ++a)
#pragma unroll
            for (int r = 0; r < 4; ++r) { ps1[a][r] = 0.f; ps2[a][r] = 0.f; }
#pragma unroll
        for (int a = 0; a < 4; ++a)
#pragma unroll
            for (int c = 0; c < NT; ++c)
#pragma unroll
                for (int r = 0; r < 4; ++r) {
                    float v = acc[a][c][r];
                    ps1[a][r] += v;
                    ps2[a][r] = __fmaf_rn(v, v, ps2[a][r]);
                }
        ln_stats(ps1, ps2, 1.f / 264);

        float gcol[NT], bcol[NT];
#pragma unroll
        for (int c = 0; c < NT; ++c) {
            int col = wc * 96 + c * 16 + lc;
            gcol[c] = (col < 264) ? g2[col] : 0.f;
            bcol[c] = (col < 264) ? b2[col] : 0.f;
        }
#pragma unroll
        for (int a = 0; a < 4; ++a)
#pragma unroll
            for (int r = 0; r < 4; ++r) {
                int rl = wr * 64 + a * 16 + lg * 4 + r;
                float mu = lnMR[rl], rs = lnMR[128 + rl];
                int sx = (rl >> 1) & 3;
                int rowb = H2_OFF + rl * 576;
#pragma unroll
                for (int c = 0; c < NT; ++c) {
                    int col = wc * 96 + c * 16 + lc;
                    if (col < 288) {
                        unsigned short outv = 0;
                        if (col < 264) {
                            float v = (acc[a][c][r] - mu) * rs * gcol[c] + bcol[c];
                            outv = f2bf(mish_f(v));
                        }
                        int byte = rowb + ((col >> 5) << 6) +
                                   ((((col >> 3) & 3) ^ sx) << 4) + ((col & 7) << 1);
                        *(unsigned short*)(smem + byte) = outv;
                    }
                }
            }
        __syncthreads();
    }

    // ================= G2: h2(288) -> h3(128), +b3, LN(gh,bh), mish, |.| =================
    {
        constexpr int NT = 2;
        f32x4 acc[4][NT];
#pragma unroll
        for (int a = 0; a < 4; ++a)
#pragma unroll
            for (int c = 0; c < NT; ++c) acc[a][c] = (f32x4){0.f, 0.f, 0.f, 0.f};

        auto stage2 = [&](int t, int b) {
            int c = wu;
            const char* g = (const char*)W3p +
                ((size_t)(c * 16) * 288) * 2 + (size_t)t * 64 + vofW3;
            glds16(g, smem + (b * 8192 + c * 1024));
        };

        stage2(0, 0);
        __syncthreads();
        for (int t = 0; t < 9; ++t) {
            const int bsel = t & 1;
            if (t + 1 < 9) stage2(t + 1, bsel ^ 1);
            const char* Ab = smem + H2_OFF + (wr * 64 + lc) * 576 + t * 64 + fswz;
            const char* Bb = smem + bsel * 8192 + (wc * 32 + lc) * 64 + fswz;
            bf16x8 afr[4], bfr[NT];
#pragma unroll
            for (int a = 0; a < 4; ++a) afr[a] = *(const bf16x8*)(Ab + a * 16 * 576);
#pragma unroll
            for (int c = 0; c < NT; ++c) bfr[c] = *(const bf16x8*)(Bb + c * 1024);
            __builtin_amdgcn_s_setprio(1);
#pragma unroll
            for (int c = 0; c < NT; ++c)
#pragma unroll
                for (int a = 0; a < 4; ++a)
                    acc[a][c] = __builtin_amdgcn_mfma_f32_16x16x32_bf16(afr[a], bfr[c], acc[a][c], 0, 0, 0);
            __builtin_amdgcn_s_setprio(0);
            __syncthreads();
        }

#pragma unroll
        for (int c = 0; c < NT; ++c) {
            int col = wc * 32 + c * 16 + lc;
            float bv = b3[col];
#pragma unroll
            for (int a = 0; a < 4; ++a)
#pragma unroll
                for (int r = 0; r < 4; ++r) acc[a][c][r] += bv;
        }
        float ps1[4][4], ps2[4][4];
#pragma unroll
        for (int a = 0; a < 4; ++a)
#pragma unroll
            for (int r = 0; r < 4; ++r) { ps1[a][r] = 0.f; ps2[a][r] = 0.f; }
#pragma unroll
        for (int a = 0; a < 4; ++a)
#pragma unroll
            for (int c = 0; c < NT; ++c)
#pragma unroll
                for (int r = 0; r < 4; ++r) {
                    float v = acc[a][c][r];
                    ps1[a][r] += v;
                    ps2[a][r] = __fmaf_rn(v, v, ps2[a][r]);
                }
        ln_stats(ps1, ps2, 1.f / 128);

        float gcol[NT], bcol[NT];
#pragma unroll
        for (int c = 0; c < NT; ++c) {
            int col = wc * 32 + c * 16 + lc;
            gcol[c] = gh[col];
            bcol[c] = bh[col];
        }
        float asum = 0.f;
#pragma unroll
        for (int a = 0; a < 4; ++a)
#pragma unroll
            for (int r = 0; r < 4; ++r) {
                int rl = wr * 64 + a * 16 + lg * 4 + r;
                float mu = lnMR[rl], rs = lnMR[128 + rl];
                int sx = (rl >> 1) & 3;
                int rowb = H3_OFF + rl * 256;
#pragma unroll
                for (int c = 0; c < NT; ++c) {
                    int col = wc * 32 + c * 16 + lc;
                    float v = (acc[a][c][r] - mu) * rs * gcol[c] + bcol[c];
                    float mz = mish_f(v);
                    asum += fabsf(mz);
                    int byte = rowb + ((col >> 5) << 6) +
                               ((((col >> 3) & 3) ^ sx) << 4) + ((col & 7) << 1);
                    *(unsigned short*)(smem + byte) = f2bf(mz);
                }
            }
#pragma unroll
        for (int m = 1; m < 64; m <<= 1) asum += __shfl_xor(asum, m);
        if (lane == 0) wsum[wu] = asum;
        __syncthreads();
        if (tid == 0) {
            float s = 0.f;
            for (int w = 0; w < 8; ++w) s += wsum[w];
            partials[blockIdx.x] = s;
        }
        __syncthreads();
    }

    // ================= G3: h3(128) -> h4(264/288), LN(g3,b3n), mish =================
    {
        constexpr int NT = 6;
        f32x4 acc[4][NT];
#pragma unroll
        for (int a = 0; a < 4; ++a)
#pragma unroll
            for (int c = 0; c < NT; ++c) acc[a][c] = (f32x4){0.f, 0.f, 0.f, 0.f};

        auto stage3 = [&](int t, int b) {
#pragma unroll
            for (int i = 0; i < 3; ++i) {
                int c = wu + 8 * i;
                const char* g = (const char*)D1p +
                    ((size_t)(c * 16) * 128) * 2 + (size_t)t * 64 + vofD1;
                glds16(g, smem + (b * 24576 + c * 1024));
            }
        };

        stage3(0, 0);
        __syncthreads();
        for (int t = 0; t < 4; ++t) {
            const int bsel = t & 1;
            if (t + 1 < 4) stage3(t + 1, bsel ^ 1);
            const char* Ab = smem + H3_OFF + (wr * 64 + lc) * 256 + t * 64 + fswz;
            const char* Bb = smem + bsel * 24576 + (wc * 96 + lc) * 64 + fswz;
            bf16x8 afr[4], bfr[NT];
#pragma unroll
            for (int a = 0; a < 4; ++a) afr[a] = *(const bf16x8*)(Ab + a * 16 * 256);
#pragma unroll
            for (int c = 0; c < NT; ++c) bfr[c] = *(const bf16x8*)(Bb + c * 1024);
            __builtin_amdgcn_s_setprio(1);
#pragma unroll
            for (int c = 0; c < NT; ++c)
#pragma unroll
                for (int a = 0; a < 4; ++a)
                    acc[a][c] = __builtin_amdgcn_mfma_f32_16x16x32_bf16(afr[a], bfr[c], acc[a][c], 0, 0, 0);
            __builtin_amdgcn_s_setprio(0);
            __syncthreads();
        }

        float ps1[4][4], ps2[4][4];
#pragma unroll
        for (int a = 0; a < 4; ++a)
#pragma unroll
            for (int r = 0; r < 4; ++r) { ps1[a][r] = 0.f; ps2[a][r] = 0.f; }
#pragma unroll
        for (int a = 0; a < 4; ++a)
#pragma unroll
            for (int c = 0; c < NT; ++c)
#pragma unroll
                for (int r = 0; r < 4; ++r) {
                    float v = acc[a][c][r];
                    ps1[a][r] += v;
                    ps2[a][r] = __fmaf_rn(v, v, ps2[a][r]);
                }
        ln_stats(ps1, ps2, 1.f / 264);

        float gcol[NT], bcol[NT];
#pragma unroll
        for (int c = 0; c < NT; ++c) {
            int col = wc * 96 + c * 16 + lc;
            gcol[c] = (col < 264) ? g3[col] : 0.f;
            bcol[c] = (col < 264) ? b3n[col] : 0.f;
        }
#pragma unroll
        for (int a = 0; a < 4; ++a)
#pragma unroll
            for (int r = 0; r < 4; ++r) {
                int rl = wr * 64 + a * 16 + lg * 4 + r;
                float mu = lnMR[rl], rs = lnMR[128 + rl];
                int sx = (rl >> 1) & 3;
                int rowb = H4_OFF + rl * 576;
#pragma unroll
                for (int c = 0; c < NT; ++c) {
                    int col = wc * 96 + c * 16 + lc;
                    if (col < 288) {
                        unsigned short outv = 0;
                        if (col < 264) {
                            float v = (acc[a][c][r] - mu) * rs * gcol[c] + bcol[c];
                            outv = f2bf(mish_f(v));
                        }
                        int byte = rowb + ((col >> 5) << 6) +
                                   ((((col >> 3) & 3) ^ sx) << 4) + ((col & 7) << 1);
                        *(unsigned short*)(smem + byte) = outv;
                    }
                }
            }
        __syncthreads();
    }

    // ================= G4: h4(288) -> actH(512), LN(g4,b4), mish =================
    {
        constexpr int NT = 8;
        f32x4 acc[4][NT];
#pragma unroll
        for (int a = 0; a < 4; ++a)
#pragma unroll
            for (int c = 0; c < NT; ++c) acc[a][c] = (f32x4){0.f, 0.f, 0.f, 0.f};

        auto stage4 = [&](int t) {
#pragma unroll
            for (int i = 0; i < 4; ++i) {
                int c = wu + 8 * i;
                const char* g = (const char*)D2p +
                    ((size_t)(c * 16) * 320) * 2 + (size_t)t * 64 + vofW5;
                glds16(g, smem + (W5_OFF + c * 1024));
            }
        };

        for (int t = 0; t < 9; ++t) {
            stage4(t);
            __syncthreads();
            const char* Ab = smem + H4_OFF + (wr * 64 + lc) * 576 + t * 64 + fswz;
            const char* Bb = smem + W5_OFF + (wc * 128 + lc) * 64 + fswz;
            bf16x8 afr[4], bfr[NT];
#pragma unroll
            for (int a = 0; a < 4; ++a) afr[a] = *(const bf16x8*)(Ab + a * 16 * 576);
#pragma unroll
            for (int c = 0; c < NT; ++c) bfr[c] = *(const bf16x8*)(Bb + c * 1024);
            __builtin_amdgcn_s_setprio(1);
#pragma unroll
            for (int c = 0; c < NT; ++c)
#pragma unroll
                for (int a = 0; a < 4; ++a)
                    acc[a][c] = __builtin_amdgcn_mfma_f32_16x16x32_bf16(afr[a], bfr[c], acc[a][c], 0, 0, 0);
            __builtin_amdgcn_s_setprio(0);
            __syncthreads();
        }

        float ps1[4][4], ps2[4][4];
#pragma unroll
        for (int a = 0; a < 4; ++a)
#pragma unroll
            for (int r = 0; r < 4; ++r) { ps1[a][r] = 0.f; ps2[a][r] = 0.f; }
#pragma unroll
        for (int a = 0; a < 4; ++a)
#pragma unroll
            for (int c = 0; c < NT; ++c)
#pragma unroll
                for (int r = 0; r < 4; ++r) {
                    float v = acc[a][c][r];
                    ps1[a][r] += v;
                    ps2[a][r] = __fmaf_rn(v, v, ps2[a][r]);
                }
        ln_stats(ps1, ps2, 1.f / 512);

        float gcol[NT], bcol[NT];
#pragma unroll
        for (int c = 0; c < NT; ++c) {
            int col = wc * 128 + c * 16 + lc;
            gcol[c] = g4[col];
            bcol[c] = b4[col];
        }
#pragma unroll
        for (int a = 0; a < 4; ++a)
#pragma unroll
            for (int r = 0; r < 4; ++r) {
                int rl = wr * 64 + a * 16 + lg * 4 + r;
                float mu = lnMR[rl], rs = lnMR[128 + rl];
                size_t rowoff = (size_t)(row0 + rl) * 512;
#pragma unroll
                for (int c = 0; c < NT; ++c) {
                    int col = wc * 128 + c * 16 + lc;
                    float v = (acc[a][c][r] - mu) * rs * gcol[c] + bcol[c];
                    actH[rowoff + col] = f2bf(mish_f(v));
                }
            }
    }
}

// ---------------- deterministic reduction of |latent| partials ----------------
__global__ void reduce_abs(const float* __restrict__ partials, float* __restrict__ out) {
    __shared__ float sm[256];
    float s = 0.f;
    for (int i = threadIdx.x; i < 512; i += 256) s += partials[i];  // fixed order
    sm[threadIdx.x] = s;
    __syncthreads();
    for (int step = 128; step > 0; step >>= 1) {
        if (threadIdx.x < step) sm[threadIdx.x] += sm[threadIdx.x + step];
        __syncthreads();
    }
    if (threadIdx.x == 0) out[0] = sm[0];
}

extern "C" void kernel_launch(void* const* d_in, const int* in_sizes, int n_in,
                              void* d_out, int out_size, void* d_ws, size_t ws_size,
                              hipStream_t stream)
{
    const float* x   = (const float*)d_in[0];
    const float* W1  = (const float*)d_in[1];
    const float* g1  = (const float*)d_in[2];
    const float* b1  = (const float*)d_in[3];
    const float* W2  = (const float*)d_in[4];
    const float* g2  = (const float*)d_in[5];
    const float* b2  = (const float*)d_in[6];
    const float* W3  = (const float*)d_in[7];
    const float* b3  = (const float*)d_in[8];
    const float* gh  = (const float*)d_in[9];
    const float* bh  = (const float*)d_in[10];
    const float* D1  = (const float*)d_in[11];
    const float* g3  = (const float*)d_in[12];
    const float* b3n = (const float*)d_in[13];
    const float* D2  = (const float*)d_in[14];
    const float* g4  = (const float*)d_in[15];
    const float* b4  = (const float*)d_in[16];
    const float* D3  = (const float*)d_in[17];
    const float* bo  = (const float*)d_in[18];

    char* ws = (char*)d_ws;
    size_t off = 0;
    auto alloc = [&](size_t bytes) -> char* {
        char* p = ws + off;
        off += (bytes + 255) & ~(size_t)255;
        return p;
    };
    unsigned short* W1p = (unsigned short*)alloc((size_t)512 * 832 * 2);
    unsigned short* W2p = (unsigned short*)alloc((size_t)384 * 512 * 2);
    unsigned short* W3p = (unsigned short*)alloc((size_t)128 * 288 * 2);
    unsigned short* D1p = (unsigned short*)alloc((size_t)384 * 128 * 2);
    unsigned short* D2p = (unsigned short*)alloc((size_t)512 * 320 * 2);
    unsigned short* D3p = (unsigned short*)alloc((size_t)896 * 512 * 2);
    unsigned short* actP = (unsigned short*)alloc((size_t)B_ROWS * 512 * 2);
    unsigned short* actH = (unsigned short*)alloc((size_t)B_ROWS * 512 * 2);
    float* partials = (float*)alloc(512 * 4);

    CvtArgs ca;
    ca.src[0] = W1; ca.dst[0] = W1p; ca.O[0] = 512; ca.K[0] = 784; ca.KP[0] = 832;
    ca.src[1] = W2; ca.dst[1] = W2p; ca.O[1] = 264; ca.K[1] = 512; ca.KP[1] = 512;
    ca.src[2] = W3; ca.dst[2] = W3p; ca.O[2] = 128; ca.K[2] = 264; ca.KP[2] = 288;
    ca.src[3] = D1; ca.dst[3] = D1p; ca.O[3] = 264; ca.K[3] = 128; ca.KP[3] = 128;
    ca.src[4] = D2; ca.dst[4] = D2p; ca.O[4] = 512; ca.K[4] = 264; ca.KP[4] = 320;
    ca.src[5] = D3; ca.dst[5] = D3p; ca.O[5] = 784; ca.K[5] = 512; ca.KP[5] = 512;
    ca.base[0] = 0;    ca.base[1] = 512;  ca.base[2] = 896;
    ca.base[3] = 1024; ca.base[4] = 1408; ca.base[5] = 1920; ca.base[6] = 2816;
    wpad_kernel<<<2816, 256, 0, stream>>>(ca);

    const int NB = B_ROWS / 128;  // 512 row-tiles

    // L1: x[.,784] @ W1^T -> 512, LN, mish   (v9, LDS 160K)
    layer9<832, 784, 512, 512, 512, 13, true,  false, false, true>
        <<<NB, 512, 0, stream>>>(x, W1p, g1, b1, nullptr, actP, nullptr);
    // L2..L5 fused: actP -> (LDS h2 -> h3 -> h4) -> actH + |latent| partials
    quad<<<NB, 512, 0, stream>>>(actP, W2p, W3p, D1p, D2p,
                                 g2, b2, gh, bh, b3, g3, b3n, g4, b4,
                                 actH, partials);
    // L6: 512 -> 784, two col-passes of BN 448 via blockIdx.y (no spill)
    dim3 g6(NB, 2);
    layer9<512, 512, 448, 784, 784, 8,  false, true,  false, false>
        <<<g6, 512, 0, stream>>>(actH, D3p, nullptr, nullptr, bo, d_out, nullptr);

    reduce_abs<<<1, 256, 0, stream>>>(partials, (float*)d_out + (size_t)B_ROWS * 784);
}

// Round 16
// 428.035 us; speedup vs baseline: 1.5152x; 1.0171x over previous
//
#include <hip/hip_runtime.h>

// AutoEncoder v16, bf16 MFMA (gfx950).
// L1: v9 kernel. L2+L3+L4+L5 fused into `quad` (h2/h3/h4 in LDS), with G4
// W-staging double-buffered (v15's G4 was serialized single-buffer).
// L6: two-pass BN=448 layer9 (no spill).

typedef short bf16x8 __attribute__((ext_vector_type(8)));
typedef float f32x4  __attribute__((ext_vector_type(4)));

#define B_ROWS 65536
#define EPS_LN 1e-5f

static __device__ __forceinline__ unsigned short f2bf(float f) {
    union { float f; unsigned u; } v; v.f = f;
    unsigned r = v.u + 0x7FFFu + ((v.u >> 16) & 1u);   // RNE
    return (unsigned short)(r >> 16);
}

static __device__ __forceinline__ float mish_f(float x) {
    if (x > 15.f) return x;
    float u = __expf(x);
    float p = __fmaf_rn(u, u, 2.f * u);
    return x * (p / (p + 2.f));
}

// direct global->LDS, 16B per lane; LDS base must be wave-uniform
static __device__ __forceinline__ void glds16(const void* g, void* l) {
    typedef __attribute__((address_space(3))) unsigned lds_u32;
    typedef __attribute__((address_space(1))) const unsigned glb_u32;
    lds_u32* lp = (lds_u32*)l;
    unsigned lofs = __builtin_amdgcn_readfirstlane((unsigned)(unsigned long long)lp);
    lp = (lds_u32*)(unsigned long long)lofs;
    __builtin_amdgcn_global_load_lds((glb_u32*)g, lp, 16, 0, 0);
}

// ---------------- padded weight fp32->bf16 conversion ----------------
struct CvtArgs {
    const float* src[6];
    unsigned short* dst[6];
    int O[6], K[6], KP[6];
    int base[7];
};

__global__ void wpad_kernel(CvtArgs a) {
    int b = blockIdx.x;
    int seg = 0;
    while (b >= a.base[seg + 1]) ++seg;
    int r = b - a.base[seg];
    int O = a.O[seg], K = a.K[seg], KP = a.KP[seg];
    const float* s = a.src[seg];
    unsigned short* d = a.dst[seg];
    for (int c = threadIdx.x; c < KP; c += 256) {
        unsigned short v = 0;
        if (r < O && c < K) v = f2bf(s[(size_t)r * K + c]);
        d[(size_t)r * KP + c] = v;
    }
}

// ---------------- v9 fused layer kernel (BK=64) — L1 and L6 ----------------
template<int KP, int ASTR, int BN, int OREAL, int OSTRIDE, int NKT,
         bool SRCF32, bool HASBIAS, bool ABS, bool LN>
__global__ __launch_bounds__(512, 2)
void layer9(const void* __restrict__ Asrc,
            const unsigned short* __restrict__ Wp,
            const float* __restrict__ gam,
            const float* __restrict__ bet,
            const float* __restrict__ bias,
            void* __restrict__ Aout,
            float* __restrict__ partials)
{
    constexpr int NT   = BN / 64;
    constexpr int NCHW = BN / 8;
    constexpr int NCH  = NCHW + (SRCF32 ? 0 : 16);
    constexpr int MAXC = (NCH + 7) / 8;
    constexpr int ABY  = 128 * 128;
    constexpr int WBY  = BN * 128;

    __shared__ __align__(16) char smem[2 * ABY + 2 * WBY];

    const int tid  = threadIdx.x;
    const int lane = tid & 63;
    const int wu   = __builtin_amdgcn_readfirstlane(tid >> 6);
    const int wr = wu >> 2, wc = wu & 3;
    const int lg = lane >> 4, lc = lane & 15;
    const int row0  = blockIdx.x * 128;
    const int cbase = LN ? 0 : blockIdx.y * BN;

    const int crow = lane >> 3;
    const int sg   = (lane & 7) ^ crow;
    const size_t vofW = ((size_t)crow * KP + (size_t)(sg << 3)) * 2;
    const size_t vofA = ((size_t)crow * ASTR + (size_t)(sg << 3)) * 2;

    auto stage = [&](int t, int b) {
#pragma unroll
        for (int i = 0; i < MAXC; ++i) {
            int c = wu + 8 * i;
            if (c < NCHW) {
                const char* g = (const char*)Wp +
                    ((size_t)(cbase + c * 8) * KP) * 2 + (size_t)t * 128 + vofW;
                glds16(g, smem + (2 * ABY + b * WBY + c * 1024));
            } else if (c < NCH) {
                int ca = c - NCHW;
                const char* g = (const char*)Asrc +
                    ((size_t)(row0 + ca * 8) * ASTR) * 2 + (size_t)t * 128 + vofA;
                glds16(g, smem + (b * ABY + ca * 1024));
            }
        }
    };

    const int ar = tid >> 2, as = tid & 3;
    const float* axp = (const float*)Asrc + (size_t)(row0 + ar) * ASTR + as * 16;
    float4 rA[4];
#pragma unroll
    for (int j = 0; j < 4; ++j) rA[j] = make_float4(0, 0, 0, 0);

    auto loadA1 = [&](int t) {
#pragma unroll
        for (int j = 0; j < 4; ++j) {
            int c0 = t * 64 + as * 16 + j * 4;
            rA[j] = (c0 + 3 < 784) ? *(const float4*)(axp + t * 64 + j * 4)
                                   : make_float4(0, 0, 0, 0);
        }
    };
    auto pubA = [&](int b) {
        union { unsigned short us[8]; uint4 v; } u0, u1;
        u0.us[0] = f2bf(rA[0].x); u0.us[1] = f2bf(rA[0].y);
        u0.us[2] = f2bf(rA[0].z); u0.us[3] = f2bf(rA[0].w);
        u0.us[4] = f2bf(rA[1].x); u0.us[5] = f2bf(rA[1].y);
        u0.us[6] = f2bf(rA[1].z); u0.us[7] = f2bf(rA[1].w);
        u1.us[0] = f2bf(rA[2].x); u1.us[1] = f2bf(rA[2].y);
        u1.us[2] = f2bf(rA[2].z); u1.us[3] = f2bf(rA[2].w);
        u1.us[4] = f2bf(rA[3].x); u1.us[5] = f2bf(rA[3].y);
        u1.us[6] = f2bf(rA[3].z); u1.us[7] = f2bf(rA[3].w);
        int s0 = as * 2, rb = b * ABY + ar * 128, rx = ar & 7;
        *(uint4*)(smem + rb + (((s0    ) ^ rx) << 4)) = u0.v;
        *(uint4*)(smem + rb + (((s0 + 1) ^ rx) << 4)) = u1.v;
    };

    stage(0, 0);
    if constexpr (SRCF32) { loadA1(0); pubA(0); }
    __syncthreads();

    f32x4 acc[4][NT];
#pragma unroll
    for (int a = 0; a < 4; ++a)
#pragma unroll
        for (int c = 0; c < NT; ++c) acc[a][c] = (f32x4){0.f, 0.f, 0.f, 0.f};

    const int f0 = ((lg ^ (lc & 7)) << 4);

    for (int t = 0; t < NKT; ++t) {
        const int bsel = t & 1;
        if (t + 1 < NKT) {
            stage(t + 1, bsel ^ 1);
            if constexpr (SRCF32) loadA1(t + 1);
        }
        const char* Ab = smem + bsel * ABY + (wr * 64 + lc) * 128;
        const char* Bb = smem + 2 * ABY + bsel * WBY + (wc * NT * 16 + lc) * 128;
#pragma unroll
        for (int h = 0; h < 2; ++h) {
            const int fh = f0 ^ (h << 6);
            bf16x8 afr[4], bfr[NT];
#pragma unroll
            for (int a = 0; a < 4; ++a)
                afr[a] = *(const bf16x8*)(Ab + a * 2048 + fh);
#pragma unroll
            for (int c = 0; c < NT; ++c)
                bfr[c] = *(const bf16x8*)(Bb + c * 2048 + fh);
            __builtin_amdgcn_s_setprio(1);
#pragma unroll
            for (int c = 0; c < NT; ++c)
#pragma unroll
                for (int a = 0; a < 4; ++a)
                    acc[a][c] = __builtin_amdgcn_mfma_f32_16x16x32_bf16(afr[a], bfr[c], acc[a][c], 0, 0, 0);
            __builtin_amdgcn_s_setprio(0);
        }
        if constexpr (SRCF32) { if (t + 1 < NKT) pubA(bsel ^ 1); }
        __syncthreads();
    }

    if constexpr (LN) {
        if constexpr (HASBIAS) {
#pragma unroll
            for (int c = 0; c < NT; ++c) {
                int col = wc * NT * 16 + c * 16 + lc;
                float bv = (col < OREAL) ? bias[col] : 0.f;
#pragma unroll
                for (int a = 0; a < 4; ++a)
#pragma unroll
                    for (int r = 0; r < 4; ++r) acc[a][c][r] += bv;
            }
        }
        float ps1[4][4], ps2[4][4];
#pragma unroll
        for (int a = 0; a < 4; ++a)
#pragma unroll
            for (int r = 0; r < 4; ++r) { ps1[a][r] = 0.f; ps2[a][r] = 0.f; }
#pragma unroll
        for (int a = 0; a < 4; ++a)
#pragma unroll
            for (int c = 0; c < NT; ++c)
#pragma unroll
                for (int r = 0; r < 4; ++r) {
                    float v = acc[a][c][r];
                    ps1[a][r] += v;
                    ps2[a][r] = __fmaf_rn(v, v, ps2[a][r]);
                }
#pragma unroll
        for (int m = 1; m < 16; m <<= 1)
#pragma unroll
            for (int a = 0; a < 4; ++a)
#pragma unroll
                for (int r = 0; r < 4; ++r) {
                    ps1[a][r] += __shfl_xor(ps1[a][r], m);
                    ps2[a][r] += __shfl_xor(ps2[a][r], m);
                }

        float* lnP  = (float*)smem;
        float* lnMR = (float*)(smem + 4096);
        float* wsum = (float*)(smem + 5120);

        if (lc == 0) {
#pragma unroll
            for (int a = 0; a < 4; ++a)
#pragma unroll
                for (int r = 0; r < 4; ++r) {
                    int row = wr * 64 + a * 16 + lg * 4 + r;
                    lnP[row * 4 + wc]       = ps1[a][r];
                    lnP[512 + row * 4 + wc] = ps2[a][r];
                }
        }
        __syncthreads();
        if (tid < 128) {
            float s1 = lnP[tid * 4] + lnP[tid * 4 + 1] + lnP[tid * 4 + 2] + lnP[tid * 4 + 3];
            float s2 = lnP[512 + tid * 4] + lnP[512 + tid * 4 + 1] +
                       lnP[512 + tid * 4 + 2] + lnP[512 + tid * 4 + 3];
            float mu = s1 * (1.f / OREAL);
            float var = fmaxf(s2 * (1.f / OREAL) - mu * mu, 0.f);
            lnMR[tid]       = mu;
            lnMR[128 + tid] = rsqrtf(var + EPS_LN);
        }
        __syncthreads();

        float gcol[NT], bcol[NT];
#pragma unroll
        for (int c = 0; c < NT; ++c) {
            int col = wc * NT * 16 + c * 16 + lc;
            gcol[c] = (col < OREAL) ? gam[col] : 0.f;
            bcol[c] = (col < OREAL) ? bet[col] : 0.f;
        }

        float asum = 0.f;
        unsigned short* outp = (unsigned short*)Aout;
#pragma unroll
        for (int a = 0; a < 4; ++a)
#pragma unroll
            for (int r = 0; r < 4; ++r) {
                int rl = wr * 64 + a * 16 + lg * 4 + r;
                float mu = lnMR[rl], rs = lnMR[128 + rl];
                size_t rowoff = (size_t)(row0 + rl) * OSTRIDE;
#pragma unroll
                for (int c = 0; c < NT; ++c) {
                    int col = wc * NT * 16 + c * 16 + lc;
                    if (col < OSTRIDE) {
                        unsigned short outv = 0;
                        if (col < OREAL) {
                            float v = (acc[a][c][r] - mu) * rs * gcol[c] + bcol[c];
                            float mz = mish_f(v);
                            if (ABS) asum += fabsf(mz);
                            outv = f2bf(mz);
                        }
                        outp[rowoff + col] = outv;
                    }
                }
            }

        if constexpr (ABS) {
#pragma unroll
            for (int m = 1; m < 64; m <<= 1) asum += __shfl_xor(asum, m);
            if (lane == 0) wsum[wu] = asum;
            __syncthreads();
            if (tid == 0) {
                float s = 0.f;
                for (int w = 0; w < 8; ++w) s += wsum[w];
                partials[blockIdx.x] = s;
            }
        }
    } else {
        float* outp = (float*)Aout;
#pragma unroll
        for (int c = 0; c < NT; ++c) {
            int col = cbase + wc * NT * 16 + c * 16 + lc;
            bool ok = col < OREAL;
            float bv = ok ? bias[col] : 0.f;
#pragma unroll
            for (int a = 0; a < 4; ++a)
#pragma unroll
                for (int r = 0; r < 4; ++r) {
                    if (ok) {
                        int rl = wr * 64 + a * 16 + lg * 4 + r;
                        float v = acc[a][c][r] + bv;
                        outp[(size_t)(row0 + rl) * OSTRIDE + col] = 1.f / (1.f + __expf(-v));
                    }
                }
        }
    }
}

// ---------------- quad kernel: L2+L3+L4+L5 fused, activations in LDS ----------------
// LDS lifetime map (bytes):
//  G1: A1 dbuf [0,16K)      W2 dbuf [16K,64K)   h2 -> [64K,136K)  str 576
//  G2: W3 dbuf [0,16K)      h2 in   [64K,136K)  h3 -> [120K,152K) str 256
//  G3: D1 dbuf [0,48K)      h3 in   [120K,152K) h4 -> [48K,120K)  str 576
//  G4: W5 dbuf buf0@[0,32K) buf1@[120K,152K)    h4 in [48K,120K)  -> actH
//  LN scratch: [152K,157K)  (dedicated, all phases)
#define H2_OFF  65536
#define H3_OFF  122880
#define H4_OFF  49152
#define W5_B0   0
#define W5_B1   122880
#define LN_OFF  155648

__global__ __launch_bounds__(512, 2)
void quad(const unsigned short* __restrict__ actP,
          const unsigned short* __restrict__ W2p,   // [384][512]
          const unsigned short* __restrict__ W3p,   // [128][288]
          const unsigned short* __restrict__ D1p,   // [384][128]
          const unsigned short* __restrict__ D2p,   // [512][320]
          const float* __restrict__ g2, const float* __restrict__ b2,
          const float* __restrict__ gh, const float* __restrict__ bh,
          const float* __restrict__ b3,
          const float* __restrict__ g3, const float* __restrict__ b3n,
          const float* __restrict__ g4, const float* __restrict__ b4,
          unsigned short* __restrict__ actH,        // [B][512]
          float* __restrict__ partials)
{
    __shared__ __align__(16) char smem[160800];

    const int tid  = threadIdx.x;
    const int lane = tid & 63;
    const int wu   = __builtin_amdgcn_readfirstlane(tid >> 6);
    const int wr = wu >> 2, wc = wu & 3;
    const int lg = lane >> 4, lc = lane & 15;
    const int row0 = blockIdx.x * 128;

    const int sgl = (lane & 3) ^ ((lane >> 3) & 3);
    const size_t vofA  = ((size_t)(lane >> 2) * 512 + (size_t)(sgl << 3)) * 2;
    const size_t vofW2 = vofA;
    const size_t vofW3 = ((size_t)(lane >> 2) * 288 + (size_t)(sgl << 3)) * 2;
    const size_t vofD1 = ((size_t)(lane >> 2) * 128 + (size_t)(sgl << 3)) * 2;
    const size_t vofW5 = ((size_t)(lane >> 2) * 320 + (size_t)(sgl << 3)) * 2;

    const int fswz = ((lg ^ ((lc >> 1) & 3)) << 4);

    float* lnP  = (float*)(smem + LN_OFF);
    float* lnMR = (float*)(smem + LN_OFF + 4096);
    float* wsum = (float*)(smem + LN_OFF + 5120);

    auto ln_stats = [&](float ps1[4][4], float ps2[4][4], float invO) {
#pragma unroll
        for (int m = 1; m < 16; m <<= 1)
#pragma unroll
            for (int a = 0; a < 4; ++a)
#pragma unroll
                for (int r = 0; r < 4; ++r) {
                    ps1[a][r] += __shfl_xor(ps1[a][r], m);
                    ps2[a][r] += __shfl_xor(ps2[a][r], m);
                }
        if (lc == 0) {
#pragma unroll
            for (int a = 0; a < 4; ++a)
#pragma unroll
                for (int r = 0; r < 4; ++r) {
                    int row = wr * 64 + a * 16 + lg * 4 + r;
                    lnP[row * 4 + wc]       = ps1[a][r];
                    lnP[512 + row * 4 + wc] = ps2[a][r];
                }
        }
        __syncthreads();
        if (tid < 128) {
            float s1 = lnP[tid * 4] + lnP[tid * 4 + 1] + lnP[tid * 4 + 2] + lnP[tid * 4 + 3];
            float s2 = lnP[512 + tid * 4] + lnP[512 + tid * 4 + 1] +
                       lnP[512 + tid * 4 + 2] + lnP[512 + tid * 4 + 3];
            float mu = s1 * invO;
            float var = fmaxf(s2 * invO - mu * mu, 0.f);
            lnMR[tid]       = mu;
            lnMR[128 + tid] = rsqrtf(var + EPS_LN);
        }
        __syncthreads();
    };

    // ================= G1: actP(512) -> h2(264/288), LN(g2,b2), mish =================
    {
        constexpr int NT = 6;
        f32x4 acc[4][NT];
#pragma unroll
        for (int a = 0; a < 4; ++a)
#pragma unroll
            for (int c = 0; c < NT; ++c) acc[a][c] = (f32x4){0.f, 0.f, 0.f, 0.f};

        auto stage1 = [&](int t, int b) {
#pragma unroll
            for (int i = 0; i < 4; ++i) {
                int c = wu + 8 * i;
                if (c < 24) {
                    const char* g = (const char*)W2p +
                        ((size_t)(c * 16) * 512) * 2 + (size_t)t * 64 + vofW2;
                    glds16(g, smem + (16384 + b * 24576 + c * 1024));
                } else {
                    int ca = c - 24;
                    const char* g = (const char*)actP +
                        ((size_t)(row0 + ca * 16) * 512) * 2 + (size_t)t * 64 + vofA;
                    glds16(g, smem + (b * 8192 + ca * 1024));
                }
            }
        };

        stage1(0, 0);
        __syncthreads();
        for (int t = 0; t < 16; ++t) {
            const int bsel = t & 1;
            if (t + 1 < 16) stage1(t + 1, bsel ^ 1);
            const char* Ab = smem + bsel * 8192 + (wr * 64 + lc) * 64 + fswz;
            const char* Bb = smem + 16384 + bsel * 24576 + (wc * 96 + lc) * 64 + fswz;
            bf16x8 afr[4], bfr[NT];
#pragma unroll
            for (int a = 0; a < 4; ++a) afr[a] = *(const bf16x8*)(Ab + a * 1024);
#pragma unroll
            for (int c = 0; c < NT; ++c) bfr[c] = *(const bf16x8*)(Bb + c * 1024);
            __builtin_amdgcn_s_setprio(1);
#pragma unroll
            for (int c = 0; c < NT; ++c)
#pragma unroll
                for (int a = 0; a < 4; ++a)
                    acc[a][c] = __builtin_amdgcn_mfma_f32_16x16x32_bf16(afr[a], bfr[c], acc[a][c], 0, 0, 0);
            __builtin_amdgcn_s_setprio(0);
            __syncthreads();
        }

        float ps1[4][4], ps2[4][4];
#pragma unroll
        for (int a = 0; a < 4; ++a)
#pragma unroll
            for (int r = 0; r < 4; ++r) { ps1[a][r] = 0.f; ps2[a][r] = 0.f; }
#pragma unroll
        for (int a = 0; a < 4; ++a)
#pragma unroll
            for (int c = 0; c < NT; ++c)
#pragma unroll
                for (int r = 0; r < 4; ++r) {
                    float v = acc[a][c][r];
                    ps1[a][r] += v;
                    ps2[a][r] = __fmaf_rn(v, v, ps2[a][r]);
                }
        ln_stats(ps1, ps2, 1.f / 264);

        float gcol[NT], bcol[NT];
#pragma unroll
        for (int c = 0; c < NT; ++c) {
            int col = wc * 96 + c * 16 + lc;
            gcol[c] = (col < 264) ? g2[col] : 0.f;
            bcol[c] = (col < 264) ? b2[col] : 0.f;
        }
#pragma unroll
        for (int a = 0; a < 4; ++a)
#pragma unroll
            for (int r = 0; r < 4; ++r) {
                int rl = wr * 64 + a * 16 + lg * 4 + r;
                float mu = lnMR[rl], rs = lnMR[128 + rl];
                int sx = (rl >> 1) & 3;
                int rowb = H2_OFF + rl * 576;
#pragma unroll
                for (int c = 0; c < NT; ++c) {
                    int col = wc * 96 + c * 16 + lc;
                    if (col < 288) {
                        unsigned short outv = 0;
                        if (col < 264) {
                            float v = (acc[a][c][r] - mu) * rs * gcol[c] + bcol[c];
                            outv = f2bf(mish_f(v));
                        }
                        int byte = rowb + ((col >> 5) << 6) +
                                   ((((col >> 3) & 3) ^ sx) << 4) + ((col & 7) << 1);
                        *(unsigned short*)(smem + byte) = outv;
                    }
                }
            }
        __syncthreads();
    }

    // ================= G2: h2(288) -> h3(128), +b3, LN(gh,bh), mish, |.| =================
    {
        constexpr int NT = 2;
        f32x4 acc[4][NT];
#pragma unroll
        for (int a = 0; a < 4; ++a)
#pragma unroll
            for (int c = 0; c < NT; ++c) acc[a][c] = (f32x4){0.f, 0.f, 0.f, 0.f};

        auto stage2 = [&](int t, int b) {
            int c = wu;
            const char* g = (const char*)W3p +
                ((size_t)(c * 16) * 288) * 2 + (size_t)t * 64 + vofW3;
            glds16(g, smem + (b * 8192 + c * 1024));
        };

        stage2(0, 0);
        __syncthreads();
        for (int t = 0; t < 9; ++t) {
            const int bsel = t & 1;
            if (t + 1 < 9) stage2(t + 1, bsel ^ 1);
            const char* Ab = smem + H2_OFF + (wr * 64 + lc) * 576 + t * 64 + fswz;
            const char* Bb = smem + bsel * 8192 + (wc * 32 + lc) * 64 + fswz;
            bf16x8 afr[4], bfr[NT];
#pragma unroll
            for (int a = 0; a < 4; ++a) afr[a] = *(const bf16x8*)(Ab + a * 16 * 576);
#pragma unroll
            for (int c = 0; c < NT; ++c) bfr[c] = *(const bf16x8*)(Bb + c * 1024);
            __builtin_amdgcn_s_setprio(1);
#pragma unroll
            for (int c = 0; c < NT; ++c)
#pragma unroll
                for (int a = 0; a < 4; ++a)
                    acc[a][c] = __builtin_amdgcn_mfma_f32_16x16x32_bf16(afr[a], bfr[c], acc[a][c], 0, 0, 0);
            __builtin_amdgcn_s_setprio(0);
            __syncthreads();
        }

#pragma unroll
        for (int c = 0; c < NT; ++c) {
            int col = wc * 32 + c * 16 + lc;
            float bv = b3[col];
#pragma unroll
            for (int a = 0; a < 4; ++a)
#pragma unroll
                for (int r = 0; r < 4; ++r) acc[a][c][r] += bv;
        }
        float ps1[4][4], ps2[4][4];
#pragma unroll
        for (int a = 0; a < 4; ++a)
#pragma unroll
            for (int r = 0; r < 4; ++r) { ps1[a][r] = 0.f; ps2[a][r] = 0.f; }
#pragma unroll
        for (int a = 0; a < 4; ++a)
#pragma unroll
            for (int c = 0; c < NT; ++c)
#pragma unroll
                for (int r = 0; r < 4; ++r) {
                    float v = acc[a][c][r];
                    ps1[a][r] += v;
                    ps2[a][r] = __fmaf_rn(v, v, ps2[a][r]);
                }
        ln_stats(ps1, ps2, 1.f / 128);

        float gcol[NT], bcol[NT];
#pragma unroll
        for (int c = 0; c < NT; ++c) {
            int col = wc * 32 + c * 16 + lc;
            gcol[c] = gh[col];
            bcol[c] = bh[col];
        }
        float asum = 0.f;
#pragma unroll
        for (int a = 0; a < 4; ++a)
#pragma unroll
            for (int r = 0; r < 4; ++r) {
                int rl = wr * 64 + a * 16 + lg * 4 + r;
                float mu = lnMR[rl], rs = lnMR[128 + rl];
                int sx = (rl >> 1) & 3;
                int rowb = H3_OFF + rl * 256;
#pragma unroll
                for (int c = 0; c < NT; ++c) {
                    int col = wc * 32 + c * 16 + lc;
                    float v = (acc[a][c][r] - mu) * rs * gcol[c] + bcol[c];
                    float mz = mish_f(v);
                    asum += fabsf(mz);
                    int byte = rowb + ((col >> 5) << 6) +
                               ((((col >> 3) & 3) ^ sx) << 4) + ((col & 7) << 1);
                    *(unsigned short*)(smem + byte) = f2bf(mz);
                }
            }
#pragma unroll
        for (int m = 1; m < 64; m <<= 1) asum += __shfl_xor(asum, m);
        if (lane == 0) wsum[wu] = asum;
        __syncthreads();
        if (tid == 0) {
            float s = 0.f;
            for (int w = 0; w < 8; ++w) s += wsum[w];
            partials[blockIdx.x] = s;
        }
        __syncthreads();
    }

    // ================= G3: h3(128) -> h4(264/288), LN(g3,b3n), mish =================
    {
        constexpr int NT = 6;
        f32x4 acc[4][NT];
#pragma unroll
        for (int a = 0; a < 4; ++a)
#pragma unroll
            for (int c = 0; c < NT; ++c) acc[a][c] = (f32x4){0.f, 0.f, 0.f, 0.f};

        auto stage3 = [&](int t, int b) {
#pragma unroll
            for (int i = 0; i < 3; ++i) {
                int c = wu + 8 * i;
                const char* g = (const char*)D1p +
                    ((size_t)(c * 16) * 128) * 2 + (size_t)t * 64 + vofD1;
                glds16(g, smem + (b * 24576 + c * 1024));
            }
        };

        stage3(0, 0);
        __syncthreads();
        for (int t = 0; t < 4; ++t) {
            const int bsel = t & 1;
            if (t + 1 < 4) stage3(t + 1, bsel ^ 1);
            const char* Ab = smem + H3_OFF + (wr * 64 + lc) * 256 + t * 64 + fswz;
            const char* Bb = smem + bsel * 24576 + (wc * 96 + lc) * 64 + fswz;
            bf16x8 afr[4], bfr[NT];
#pragma unroll
            for (int a = 0; a < 4; ++a) afr[a] = *(const bf16x8*)(Ab + a * 16 * 256);
#pragma unroll
            for (int c = 0; c < NT; ++c) bfr[c] = *(const bf16x8*)(Bb + c * 1024);
            __builtin_amdgcn_s_setprio(1);
#pragma unroll
            for (int c = 0; c < NT; ++c)
#pragma unroll
                for (int a = 0; a < 4; ++a)
                    acc[a][c] = __builtin_amdgcn_mfma_f32_16x16x32_bf16(afr[a], bfr[c], acc[a][c], 0, 0, 0);
            __builtin_amdgcn_s_setprio(0);
            __syncthreads();
        }

        float ps1[4][4], ps2[4][4];
#pragma unroll
        for (int a = 0; a < 4; ++a)
#pragma unroll
            for (int r = 0; r < 4; ++r) { ps1[a][r] = 0.f; ps2[a][r] = 0.f; }
#pragma unroll
        for (int a = 0; a < 4; ++a)
#pragma unroll
            for (int c = 0; c < NT; ++c)
#pragma unroll
                for (int r = 0; r < 4; ++r) {
                    float v = acc[a][c][r];
                    ps1[a][r] += v;
                    ps2[a][r] = __fmaf_rn(v, v, ps2[a][r]);
                }
        ln_stats(ps1, ps2, 1.f / 264);

        float gcol[NT], bcol[NT];
#pragma unroll
        for (int c = 0; c < NT; ++c) {
            int col = wc * 96 + c * 16 + lc;
            gcol[c] = (col < 264) ? g3[col] : 0.f;
            bcol[c] = (col < 264) ? b3n[col] : 0.f;
        }
#pragma unroll
        for (int a = 0; a < 4; ++a)
#pragma unroll
            for (int r = 0; r < 4; ++r) {
                int rl = wr * 64 + a * 16 + lg * 4 + r;
                float mu = lnMR[rl], rs = lnMR[128 + rl];
                int sx = (rl >> 1) & 3;
                int rowb = H4_OFF + rl * 576;
#pragma unroll
                for (int c = 0; c < NT; ++c) {
                    int col = wc * 96 + c * 16 + lc;
                    if (col < 288) {
                        unsigned short outv = 0;
                        if (col < 264) {
                            float v = (acc[a][c][r] - mu) * rs * gcol[c] + bcol[c];
                            outv = f2bf(mish_f(v));
                        }
                        int byte = rowb + ((col >> 5) << 6) +
                                   ((((col >> 3) & 3) ^ sx) << 4) + ((col & 7) << 1);
                        *(unsigned short*)(smem + byte) = outv;
                    }
                }
            }
        __syncthreads();
    }

    // ================= G4: h4(288) -> actH(512), LN(g4,b4), mish =================
    // W5 double-buffered: buf0 @ [0,32K) (freed D1 region), buf1 @ [120K,152K)
    // (freed h3 region). One barrier per K-step (v9 pattern).
    {
        constexpr int NT = 8;
        f32x4 acc[4][NT];
#pragma unroll
        for (int a = 0; a < 4; ++a)
#pragma unroll
            for (int c = 0; c < NT; ++c) acc[a][c] = (f32x4){0.f, 0.f, 0.f, 0.f};

        auto stage4 = [&](int t, int b) {
            const int base = b ? W5_B1 : W5_B0;
#pragma unroll
            for (int i = 0; i < 4; ++i) {
                int c = wu + 8 * i;
                const char* g = (const char*)D2p +
                    ((size_t)(c * 16) * 320) * 2 + (size_t)t * 64 + vofW5;
                glds16(g, smem + (base + c * 1024));
            }
        };

        stage4(0, 0);
        __syncthreads();
        for (int t = 0; t < 9; ++t) {
            const int bsel = t & 1;
            if (t + 1 < 9) stage4(t + 1, bsel ^ 1);
            const char* Ab = smem + H4_OFF + (wr * 64 + lc) * 576 + t * 64 + fswz;
            const char* Bb = smem + (bsel ? W5_B1 : W5_B0) + (wc * 128 + lc) * 64 + fswz;
            bf16x8 afr[4], bfr[NT];
#pragma unroll
            for (int a = 0; a < 4; ++a) afr[a] = *(const bf16x8*)(Ab + a * 16 * 576);
#pragma unroll
            for (int c = 0; c < NT; ++c) bfr[c] = *(const bf16x8*)(Bb + c * 1024);
            __builtin_amdgcn_s_setprio(1);
#pragma unroll
            for (int c = 0; c < NT; ++c)
#pragma unroll
                for (int a = 0; a < 4; ++a)
                    acc[a][c] = __builtin_amdgcn_mfma_f32_16x16x32_bf16(afr[a], bfr[c], acc[a][c], 0, 0, 0);
            __builtin_amdgcn_s_setprio(0);
            __syncthreads();
        }

        float ps1[4][4], ps2[4][4];
#pragma unroll
        for (int a = 0; a < 4; ++a)
#pragma unroll
            for (int r = 0; r < 4; ++r) { ps1[a][r] = 0.f; ps2[a][r] = 0.f; }
#pragma unroll
        for (int a = 0; a < 4; ++a)
#pragma unroll
            for (int c = 0; c < NT; ++c)
#pragma unroll
                for (int r = 0; r < 4; ++r) {
                    float v = acc[a][c][r];
                    ps1[a][r] += v;
                    ps2[a][r] = __fmaf_rn(v, v, ps2[a][r]);
                }
        ln_stats(ps1, ps2, 1.f / 512);

        float gcol[NT], bcol[NT];
#pragma unroll
        for (int c = 0; c < NT; ++c) {
            int col = wc * 128 + c * 16 + lc;
            gcol[c] = g4[col];
            bcol[c] = b4[col];
        }
#pragma unroll
        for (int a = 0; a < 4; ++a)
#pragma unroll
            for (int r = 0; r < 4; ++r) {
                int rl = wr * 64 + a * 16 + lg * 4 + r;
                float mu = lnMR[rl], rs = lnMR[128 + rl];
                size_t rowoff = (size_t)(row0 + rl) * 512;
#pragma unroll
                for (int c = 0; c < NT; ++c) {
                    int col = wc * 128 + c * 16 + lc;
                    float v = (acc[a][c][r] - mu) * rs * gcol[c] + bcol[c];
                    actH[rowoff + col] = f2bf(mish_f(v));
                }
            }
    }
}

// ---------------- deterministic reduction of |latent| partials ----------------
__global__ void reduce_abs(const float* __restrict__ partials, float* __restrict__ out) {
    __shared__ float sm[256];
    float s = 0.f;
    for (int i = threadIdx.x; i < 512; i += 256) s += partials[i];  // fixed order
    sm[threadIdx.x] = s;
    __syncthreads();
    for (int step = 128; step > 0; step >>= 1) {
        if (threadIdx.x < step) sm[threadIdx.x] += sm[threadIdx.x + step];
        __syncthreads();
    }
    if (threadIdx.x == 0) out[0] = sm[0];
}

extern "C" void kernel_launch(void* const* d_in, const int* in_sizes, int n_in,
                              void* d_out, int out_size, void* d_ws, size_t ws_size,
                              hipStream_t stream)
{
    const float* x   = (const float*)d_in[0];
    const float* W1  = (const float*)d_in[1];
    const float* g1  = (const float*)d_in[2];
    const float* b1  = (const float*)d_in[3];
    const float* W2  = (const float*)d_in[4];
    const float* g2  = (const float*)d_in[5];
    const float* b2  = (const float*)d_in[6];
    const float* W3  = (const float*)d_in[7];
    const float* b3  = (const float*)d_in[8];
    const float* gh  = (const float*)d_in[9];
    const float* bh  = (const float*)d_in[10];
    const float* D1  = (const float*)d_in[11];
    const float* g3  = (const float*)d_in[12];
    const float* b3n = (const float*)d_in[13];
    const float* D2  = (const float*)d_in[14];
    const float* g4  = (const float*)d_in[15];
    const float* b4  = (const float*)d_in[16];
    const float* D3  = (const float*)d_in[17];
    const float* bo  = (const float*)d_in[18];

    char* ws = (char*)d_ws;
    size_t off = 0;
    auto alloc = [&](size_t bytes) -> char* {
        char* p = ws + off;
        off += (bytes + 255) & ~(size_t)255;
        return p;
    };
    unsigned short* W1p = (unsigned short*)alloc((size_t)512 * 832 * 2);
    unsigned short* W2p = (unsigned short*)alloc((size_t)384 * 512 * 2);
    unsigned short* W3p = (unsigned short*)alloc((size_t)128 * 288 * 2);
    unsigned short* D1p = (unsigned short*)alloc((size_t)384 * 128 * 2);
    unsigned short* D2p = (unsigned short*)alloc((size_t)512 * 320 * 2);
    unsigned short* D3p = (unsigned short*)alloc((size_t)896 * 512 * 2);
    unsigned short* actP = (unsigned short*)alloc((size_t)B_ROWS * 512 * 2);
    unsigned short* actH = (unsigned short*)alloc((size_t)B_ROWS * 512 * 2);
    float* partials = (float*)alloc(512 * 4);

    CvtArgs ca;
    ca.src[0] = W1; ca.dst[0] = W1p; ca.O[0] = 512; ca.K[0] = 784; ca.KP[0] = 832;
    ca.src[1] = W2; ca.dst[1] = W2p; ca.O[1] = 264; ca.K[1] = 512; ca.KP[1] = 512;
    ca.src[2] = W3; ca.dst[2] = W3p; ca.O[2] = 128; ca.K[2] = 264; ca.KP[2] = 288;
    ca.src[3] = D1; ca.dst[3] = D1p; ca.O[3] = 264; ca.K[3] = 128; ca.KP[3] = 128;
    ca.src[4] = D2; ca.dst[4] = D2p; ca.O[4] = 512; ca.K[4] = 264; ca.KP[4] = 320;
    ca.src[5] = D3; ca.dst[5] = D3p; ca.O[5] = 784; ca.K[5] = 512; ca.KP[5] = 512;
    ca.base[0] = 0;    ca.base[1] = 512;  ca.base[2] = 896;
    ca.base[3] = 1024; ca.base[4] = 1408; ca.base[5] = 1920; ca.base[6] = 2816;
    wpad_kernel<<<2816, 256, 0, stream>>>(ca);

    const int NB = B_ROWS / 128;  // 512 row-tiles

    // L1: x[.,784] @ W1^T -> 512, LN, mish   (v9, LDS 160K)
    layer9<832, 784, 512, 512, 512, 13, true,  false, false, true>
        <<<NB, 512, 0, stream>>>(x, W1p, g1, b1, nullptr, actP, nullptr);
    // L2..L5 fused: actP -> (LDS h2 -> h3 -> h4) -> actH + |latent| partials
    quad<<<NB, 512, 0, stream>>>(actP, W2p, W3p, D1p, D2p,
                                 g2, b2, gh, bh, b3, g3, b3n, g4, b4,
                                 actH, partials);
    // L6: 512 -> 784, two col-passes of BN 448 via blockIdx.y (no spill)
    dim3 g6(NB, 2);
    layer9<512, 512, 448, 784, 784, 8,  false, true,  false, false>
        <<<g6, 512, 0, stream>>>(actH, D3p, nullptr, nullptr, bo, d_out, nullptr);

    reduce_abs<<<1, 256, 0, stream>>>(partials, (float*)d_out + (size_t)B_ROWS * 784);
}

// Round 17
// 405.544 us; speedup vs baseline: 1.5992x; 1.0555x over previous
//
#include <hip/hip_runtime.h>

// AutoEncoder v17, bf16 MFMA (gfx950).
// = v13 (best: L1 v9 + trio(L2/L3/L4) + L5 v9 + L6 two-pass) with L6's grid
// swapped to (2, NB) so both col-passes of a row-tile are dispatch-adjacent
// (L2 sharing of the actH re-read).

typedef short bf16x8 __attribute__((ext_vector_type(8)));
typedef float f32x4  __attribute__((ext_vector_type(4)));

#define B_ROWS 65536
#define EPS_LN 1e-5f

static __device__ __forceinline__ unsigned short f2bf(float f) {
    union { float f; unsigned u; } v; v.f = f;
    unsigned r = v.u + 0x7FFFu + ((v.u >> 16) & 1u);   // RNE
    return (unsigned short)(r >> 16);
}

static __device__ __forceinline__ float mish_f(float x) {
    if (x > 15.f) return x;
    float u = __expf(x);
    float p = __fmaf_rn(u, u, 2.f * u);
    return x * (p / (p + 2.f));
}

// direct global->LDS, 16B per lane; LDS base must be wave-uniform
static __device__ __forceinline__ void glds16(const void* g, void* l) {
    typedef __attribute__((address_space(3))) unsigned lds_u32;
    typedef __attribute__((address_space(1))) const unsigned glb_u32;
    lds_u32* lp = (lds_u32*)l;
    unsigned lofs = __builtin_amdgcn_readfirstlane((unsigned)(unsigned long long)lp);
    lp = (lds_u32*)(unsigned long long)lofs;
    __builtin_amdgcn_global_load_lds((glb_u32*)g, lp, 16, 0, 0);
}

// ---------------- padded weight fp32->bf16 conversion ----------------
struct CvtArgs {
    const float* src[6];
    unsigned short* dst[6];
    int O[6], K[6], KP[6];
    int base[7];
};

__global__ void wpad_kernel(CvtArgs a) {
    int b = blockIdx.x;
    int seg = 0;
    while (b >= a.base[seg + 1]) ++seg;
    int r = b - a.base[seg];
    int O = a.O[seg], K = a.K[seg], KP = a.KP[seg];
    const float* s = a.src[seg];
    unsigned short* d = a.dst[seg];
    for (int c = threadIdx.x; c < KP; c += 256) {
        unsigned short v = 0;
        if (r < O && c < K) v = f2bf(s[(size_t)r * K + c]);
        d[(size_t)r * KP + c] = v;
    }
}

// ---------------- v9 fused layer kernel (BK=64) ----------------
template<int KP, int ASTR, int BN, int OREAL, int OSTRIDE, int NKT,
         bool SRCF32, bool HASBIAS, bool ABS, bool LN, bool SWAPGRID>
__global__ __launch_bounds__(512, 2)
void layer9(const void* __restrict__ Asrc,
            const unsigned short* __restrict__ Wp,
            const float* __restrict__ gam,
            const float* __restrict__ bet,
            const float* __restrict__ bias,
            void* __restrict__ Aout,
            float* __restrict__ partials)
{
    constexpr int NT   = BN / 64;
    constexpr int NCHW = BN / 8;
    constexpr int NCH  = NCHW + (SRCF32 ? 0 : 16);
    constexpr int MAXC = (NCH + 7) / 8;
    constexpr int ABY  = 128 * 128;
    constexpr int WBY  = BN * 128;

    __shared__ __align__(16) char smem[2 * ABY + 2 * WBY];

    const int tid  = threadIdx.x;
    const int lane = tid & 63;
    const int wu   = __builtin_amdgcn_readfirstlane(tid >> 6);
    const int wr = wu >> 2, wc = wu & 3;
    const int lg = lane >> 4, lc = lane & 15;
    const int row0  = (SWAPGRID ? blockIdx.y : blockIdx.x) * 128;
    const int cbase = LN ? 0 : (SWAPGRID ? blockIdx.x : blockIdx.y) * BN;

    const int crow = lane >> 3;
    const int sg   = (lane & 7) ^ crow;
    const size_t vofW = ((size_t)crow * KP + (size_t)(sg << 3)) * 2;
    const size_t vofA = ((size_t)crow * ASTR + (size_t)(sg << 3)) * 2;

    auto stage = [&](int t, int b) {
#pragma unroll
        for (int i = 0; i < MAXC; ++i) {
            int c = wu + 8 * i;
            if (c < NCHW) {
                const char* g = (const char*)Wp +
                    ((size_t)(cbase + c * 8) * KP) * 2 + (size_t)t * 128 + vofW;
                glds16(g, smem + (2 * ABY + b * WBY + c * 1024));
            } else if (c < NCH) {
                int ca = c - NCHW;
                const char* g = (const char*)Asrc +
                    ((size_t)(row0 + ca * 8) * ASTR) * 2 + (size_t)t * 128 + vofA;
                glds16(g, smem + (b * ABY + ca * 1024));
            }
        }
    };

    const int ar = tid >> 2, as = tid & 3;
    const float* axp = (const float*)Asrc + (size_t)(row0 + ar) * ASTR + as * 16;
    float4 rA[4];
#pragma unroll
    for (int j = 0; j < 4; ++j) rA[j] = make_float4(0, 0, 0, 0);

    auto loadA1 = [&](int t) {
#pragma unroll
        for (int j = 0; j < 4; ++j) {
            int c0 = t * 64 + as * 16 + j * 4;
            rA[j] = (c0 + 3 < 784) ? *(const float4*)(axp + t * 64 + j * 4)
                                   : make_float4(0, 0, 0, 0);
        }
    };
    auto pubA = [&](int b) {
        union { unsigned short us[8]; uint4 v; } u0, u1;
        u0.us[0] = f2bf(rA[0].x); u0.us[1] = f2bf(rA[0].y);
        u0.us[2] = f2bf(rA[0].z); u0.us[3] = f2bf(rA[0].w);
        u0.us[4] = f2bf(rA[1].x); u0.us[5] = f2bf(rA[1].y);
        u0.us[6] = f2bf(rA[1].z); u0.us[7] = f2bf(rA[1].w);
        u1.us[0] = f2bf(rA[2].x); u1.us[1] = f2bf(rA[2].y);
        u1.us[2] = f2bf(rA[2].z); u1.us[3] = f2bf(rA[2].w);
        u1.us[4] = f2bf(rA[3].x); u1.us[5] = f2bf(rA[3].y);
        u1.us[6] = f2bf(rA[3].z); u1.us[7] = f2bf(rA[3].w);
        int s0 = as * 2, rb = b * ABY + ar * 128, rx = ar & 7;
        *(uint4*)(smem + rb + (((s0    ) ^ rx) << 4)) = u0.v;
        *(uint4*)(smem + rb + (((s0 + 1) ^ rx) << 4)) = u1.v;
    };

    stage(0, 0);
    if constexpr (SRCF32) { loadA1(0); pubA(0); }
    __syncthreads();

    f32x4 acc[4][NT];
#pragma unroll
    for (int a = 0; a < 4; ++a)
#pragma unroll
        for (int c = 0; c < NT; ++c) acc[a][c] = (f32x4){0.f, 0.f, 0.f, 0.f};

    const int f0 = ((lg ^ (lc & 7)) << 4);

    for (int t = 0; t < NKT; ++t) {
        const int bsel = t & 1;
        if (t + 1 < NKT) {
            stage(t + 1, bsel ^ 1);
            if constexpr (SRCF32) loadA1(t + 1);
        }
        const char* Ab = smem + bsel * ABY + (wr * 64 + lc) * 128;
        const char* Bb = smem + 2 * ABY + bsel * WBY + (wc * NT * 16 + lc) * 128;
#pragma unroll
        for (int h = 0; h < 2; ++h) {
            const int fh = f0 ^ (h << 6);
            bf16x8 afr[4], bfr[NT];
#pragma unroll
            for (int a = 0; a < 4; ++a)
                afr[a] = *(const bf16x8*)(Ab + a * 2048 + fh);
#pragma unroll
            for (int c = 0; c < NT; ++c)
                bfr[c] = *(const bf16x8*)(Bb + c * 2048 + fh);
            __builtin_amdgcn_s_setprio(1);
#pragma unroll
            for (int c = 0; c < NT; ++c)
#pragma unroll
                for (int a = 0; a < 4; ++a)
                    acc[a][c] = __builtin_amdgcn_mfma_f32_16x16x32_bf16(afr[a], bfr[c], acc[a][c], 0, 0, 0);
            __builtin_amdgcn_s_setprio(0);
        }
        if constexpr (SRCF32) { if (t + 1 < NKT) pubA(bsel ^ 1); }
        __syncthreads();
    }

    if constexpr (LN) {
        if constexpr (HASBIAS) {
#pragma unroll
            for (int c = 0; c < NT; ++c) {
                int col = wc * NT * 16 + c * 16 + lc;
                float bv = (col < OREAL) ? bias[col] : 0.f;
#pragma unroll
                for (int a = 0; a < 4; ++a)
#pragma unroll
                    for (int r = 0; r < 4; ++r) acc[a][c][r] += bv;
            }
        }
        float ps1[4][4], ps2[4][4];
#pragma unroll
        for (int a = 0; a < 4; ++a)
#pragma unroll
            for (int r = 0; r < 4; ++r) { ps1[a][r] = 0.f; ps2[a][r] = 0.f; }
#pragma unroll
        for (int a = 0; a < 4; ++a)
#pragma unroll
            for (int c = 0; c < NT; ++c)
#pragma unroll
                for (int r = 0; r < 4; ++r) {
                    float v = acc[a][c][r];
                    ps1[a][r] += v;
                    ps2[a][r] = __fmaf_rn(v, v, ps2[a][r]);
                }
#pragma unroll
        for (int m = 1; m < 16; m <<= 1)
#pragma unroll
            for (int a = 0; a < 4; ++a)
#pragma unroll
                for (int r = 0; r < 4; ++r) {
                    ps1[a][r] += __shfl_xor(ps1[a][r], m);
                    ps2[a][r] += __shfl_xor(ps2[a][r], m);
                }

        float* lnP  = (float*)smem;
        float* lnMR = (float*)(smem + 4096);
        float* wsum = (float*)(smem + 5120);

        if (lc == 0) {
#pragma unroll
            for (int a = 0; a < 4; ++a)
#pragma unroll
                for (int r = 0; r < 4; ++r) {
                    int row = wr * 64 + a * 16 + lg * 4 + r;
                    lnP[row * 4 + wc]       = ps1[a][r];
                    lnP[512 + row * 4 + wc] = ps2[a][r];
                }
        }
        __syncthreads();
        if (tid < 128) {
            float s1 = lnP[tid * 4] + lnP[tid * 4 + 1] + lnP[tid * 4 + 2] + lnP[tid * 4 + 3];
            float s2 = lnP[512 + tid * 4] + lnP[512 + tid * 4 + 1] +
                       lnP[512 + tid * 4 + 2] + lnP[512 + tid * 4 + 3];
            float mu = s1 * (1.f / OREAL);
            float var = fmaxf(s2 * (1.f / OREAL) - mu * mu, 0.f);
            lnMR[tid]       = mu;
            lnMR[128 + tid] = rsqrtf(var + EPS_LN);
        }
        __syncthreads();

        float gcol[NT], bcol[NT];
#pragma unroll
        for (int c = 0; c < NT; ++c) {
            int col = wc * NT * 16 + c * 16 + lc;
            gcol[c] = (col < OREAL) ? gam[col] : 0.f;
            bcol[c] = (col < OREAL) ? bet[col] : 0.f;
        }

        float asum = 0.f;
        unsigned short* outp = (unsigned short*)Aout;
#pragma unroll
        for (int a = 0; a < 4; ++a)
#pragma unroll
            for (int r = 0; r < 4; ++r) {
                int rl = wr * 64 + a * 16 + lg * 4 + r;
                float mu = lnMR[rl], rs = lnMR[128 + rl];
                size_t rowoff = (size_t)(row0 + rl) * OSTRIDE;
#pragma unroll
                for (int c = 0; c < NT; ++c) {
                    int col = wc * NT * 16 + c * 16 + lc;
                    if (col < OSTRIDE) {
                        unsigned short outv = 0;
                        if (col < OREAL) {
                            float v = (acc[a][c][r] - mu) * rs * gcol[c] + bcol[c];
                            float mz = mish_f(v);
                            if (ABS) asum += fabsf(mz);
                            outv = f2bf(mz);
                        }
                        outp[rowoff + col] = outv;
                    }
                }
            }

        if constexpr (ABS) {
#pragma unroll
            for (int m = 1; m < 64; m <<= 1) asum += __shfl_xor(asum, m);
            if (lane == 0) wsum[wu] = asum;
            __syncthreads();
            if (tid == 0) {
                float s = 0.f;
                for (int w = 0; w < 8; ++w) s += wsum[w];
                partials[blockIdx.x] = s;
            }
        }
    } else {
        float* outp = (float*)Aout;
#pragma unroll
        for (int c = 0; c < NT; ++c) {
            int col = cbase + wc * NT * 16 + c * 16 + lc;
            bool ok = col < OREAL;
            float bv = ok ? bias[col] : 0.f;
#pragma unroll
            for (int a = 0; a < 4; ++a)
#pragma unroll
                for (int r = 0; r < 4; ++r) {
                    if (ok) {
                        int rl = wr * 64 + a * 16 + lg * 4 + r;
                        float v = acc[a][c][r] + bv;
                        outp[(size_t)(row0 + rl) * OSTRIDE + col] = 1.f / (1.f + __expf(-v));
                    }
                }
        }
    }
}

// ---------------- trio kernel: L2+L3+L4 fused, activations in LDS ----------------
__global__ __launch_bounds__(512, 2)
void trio(const unsigned short* __restrict__ actP,
          const unsigned short* __restrict__ W2p,   // [384][512]
          const unsigned short* __restrict__ W3p,   // [128][288]
          const unsigned short* __restrict__ D1p,   // [384][128]
          const float* __restrict__ g2, const float* __restrict__ b2,
          const float* __restrict__ gh, const float* __restrict__ bh,
          const float* __restrict__ b3,
          const float* __restrict__ g3, const float* __restrict__ b3n,
          unsigned short* __restrict__ actQ,        // [B][320]
          float* __restrict__ partials)
{
    __shared__ __align__(16) char smem[139264];

    const int tid  = threadIdx.x;
    const int lane = tid & 63;
    const int wu   = __builtin_amdgcn_readfirstlane(tid >> 6);
    const int wr = wu >> 2, wc = wu & 3;
    const int lg = lane >> 4, lc = lane & 15;
    const int row0 = blockIdx.x * 128;

    const int sgl = (lane & 3) ^ ((lane >> 3) & 3);
    const size_t vofA  = ((size_t)(lane >> 2) * 512 + (size_t)(sgl << 3)) * 2;
    const size_t vofW2 = vofA;
    const size_t vofW3 = ((size_t)(lane >> 2) * 288 + (size_t)(sgl << 3)) * 2;
    const size_t vofD1 = ((size_t)(lane >> 2) * 128 + (size_t)(sgl << 3)) * 2;

    const int fswz = ((lg ^ ((lc >> 1) & 3)) << 4);

    float* lnP  = (float*)smem;
    float* lnMR = (float*)(smem + 4096);
    float* wsum = (float*)(smem + 5120);

    auto ln_stats = [&](float ps1[4][4], float ps2[4][4], float invO) {
#pragma unroll
        for (int m = 1; m < 16; m <<= 1)
#pragma unroll
            for (int a = 0; a < 4; ++a)
#pragma unroll
                for (int r = 0; r < 4; ++r) {
                    ps1[a][r] += __shfl_xor(ps1[a][r], m);
                    ps2[a][r] += __shfl_xor(ps2[a][r], m);
                }
        if (lc == 0) {
#pragma unroll
            for (int a = 0; a < 4; ++a)
#pragma unroll
                for (int r = 0; r < 4; ++r) {
                    int row = wr * 64 + a * 16 + lg * 4 + r;
                    lnP[row * 4 + wc]       = ps1[a][r];
                    lnP[512 + row * 4 + wc] = ps2[a][r];
                }
        }
        __syncthreads();
        if (tid < 128) {
            float s1 = lnP[tid * 4] + lnP[tid * 4 + 1] + lnP[tid * 4 + 2] + lnP[tid * 4 + 3];
            float s2 = lnP[512 + tid * 4] + lnP[512 + tid * 4 + 1] +
                       lnP[512 + tid * 4 + 2] + lnP[512 + tid * 4 + 3];
            float mu = s1 * invO;
            float var = fmaxf(s2 * invO - mu * mu, 0.f);
            lnMR[tid]       = mu;
            lnMR[128 + tid] = rsqrtf(var + EPS_LN);
        }
        __syncthreads();
    };

    // ================= GEMM1: actP(512) -> h2(264/288), LN(g2,b2), mish =================
    {
        constexpr int NT = 6;
        f32x4 acc[4][NT];
#pragma unroll
        for (int a = 0; a < 4; ++a)
#pragma unroll
            for (int c = 0; c < NT; ++c) acc[a][c] = (f32x4){0.f, 0.f, 0.f, 0.f};

        auto stage1 = [&](int t, int b) {
#pragma unroll
            for (int i = 0; i < 4; ++i) {
                int c = wu + 8 * i;
                if (c < 24) {
                    const char* g = (const char*)W2p +
                        ((size_t)(c * 16) * 512) * 2 + (size_t)t * 64 + vofW2;
                    glds16(g, smem + (16384 + b * 24576 + c * 1024));
                } else {
                    int ca = c - 24;
                    const char* g = (const char*)actP +
                        ((size_t)(row0 + ca * 16) * 512) * 2 + (size_t)t * 64 + vofA;
                    glds16(g, smem + (b * 8192 + ca * 1024));
                }
            }
        };

        stage1(0, 0);
        __syncthreads();
        for (int t = 0; t < 16; ++t) {
            const int bsel = t & 1;
            if (t + 1 < 16) stage1(t + 1, bsel ^ 1);
            const char* Ab = smem + bsel * 8192 + (wr * 64 + lc) * 64 + fswz;
            const char* Bb = smem + 16384 + bsel * 24576 + (wc * 96 + lc) * 64 + fswz;
            bf16x8 afr[4], bfr[NT];
#pragma unroll
            for (int a = 0; a < 4; ++a) afr[a] = *(const bf16x8*)(Ab + a * 1024);
#pragma unroll
            for (int c = 0; c < NT; ++c) bfr[c] = *(const bf16x8*)(Bb + c * 1024);
            __builtin_amdgcn_s_setprio(1);
#pragma unroll
            for (int c = 0; c < NT; ++c)
#pragma unroll
                for (int a = 0; a < 4; ++a)
                    acc[a][c] = __builtin_amdgcn_mfma_f32_16x16x32_bf16(afr[a], bfr[c], acc[a][c], 0, 0, 0);
            __builtin_amdgcn_s_setprio(0);
            __syncthreads();
        }

        float ps1[4][4], ps2[4][4];
#pragma unroll
        for (int a = 0; a < 4; ++a)
#pragma unroll
            for (int r = 0; r < 4; ++r) { ps1[a][r] = 0.f; ps2[a][r] = 0.f; }
#pragma unroll
        for (int a = 0; a < 4; ++a)
#pragma unroll
            for (int c = 0; c < NT; ++c)
#pragma unroll
                for (int r = 0; r < 4; ++r) {
                    float v = acc[a][c][r];
                    ps1[a][r] += v;
                    ps2[a][r] = __fmaf_rn(v, v, ps2[a][r]);
                }
        ln_stats(ps1, ps2, 1.f / 264);

        float gcol[NT], bcol[NT];
#pragma unroll
        for (int c = 0; c < NT; ++c) {
            int col = wc * 96 + c * 16 + lc;
            gcol[c] = (col < 264) ? g2[col] : 0.f;
            bcol[c] = (col < 264) ? b2[col] : 0.f;
        }
#pragma unroll
        for (int a = 0; a < 4; ++a)
#pragma unroll
            for (int r = 0; r < 4; ++r) {
                int rl = wr * 64 + a * 16 + lg * 4 + r;
                float mu = lnMR[rl], rs = lnMR[128 + rl];
                int sx = (rl >> 1) & 3;
                int rowb = 65536 + rl * 576;
#pragma unroll
                for (int c = 0; c < NT; ++c) {
                    int col = wc * 96 + c * 16 + lc;
                    if (col < 288) {
                        unsigned short outv = 0;
                        if (col < 264) {
                            float v = (acc[a][c][r] - mu) * rs * gcol[c] + bcol[c];
                            outv = f2bf(mish_f(v));
                        }
                        int byte = rowb + ((col >> 5) << 6) +
                                   ((((col >> 3) & 3) ^ sx) << 4) + ((col & 7) << 1);
                        *(unsigned short*)(smem + byte) = outv;
                    }
                }
            }
        __syncthreads();
    }

    // ================= GEMM2: h2(288) -> h3(128), +b3, LN(gh,bh), mish, |.| =================
    {
        constexpr int NT = 2;
        f32x4 acc[4][NT];
#pragma unroll
        for (int a = 0; a < 4; ++a)
#pragma unroll
            for (int c = 0; c < NT; ++c) acc[a][c] = (f32x4){0.f, 0.f, 0.f, 0.f};

        auto stage2 = [&](int t, int b) {
            int c = wu;
            const char* g = (const char*)W3p +
                ((size_t)(c * 16) * 288) * 2 + (size_t)t * 64 + vofW3;
            glds16(g, smem + (b * 8192 + c * 1024));
        };

        stage2(0, 0);
        __syncthreads();
        for (int t = 0; t < 9; ++t) {
            const int bsel = t & 1;
            if (t + 1 < 9) stage2(t + 1, bsel ^ 1);
            const char* Ab = smem + 65536 + (wr * 64 + lc) * 576 + t * 64 + fswz;
            const char* Bb = smem + bsel * 8192 + (wc * 32 + lc) * 64 + fswz;
            bf16x8 afr[4], bfr[NT];
#pragma unroll
            for (int a = 0; a < 4; ++a) afr[a] = *(const bf16x8*)(Ab + a * 16 * 576);
#pragma unroll
            for (int c = 0; c < NT; ++c) bfr[c] = *(const bf16x8*)(Bb + c * 1024);
            __builtin_amdgcn_s_setprio(1);
#pragma unroll
            for (int c = 0; c < NT; ++c)
#pragma unroll
                for (int a = 0; a < 4; ++a)
                    acc[a][c] = __builtin_amdgcn_mfma_f32_16x16x32_bf16(afr[a], bfr[c], acc[a][c], 0, 0, 0);
            __builtin_amdgcn_s_setprio(0);
            __syncthreads();
        }

#pragma unroll
        for (int c = 0; c < NT; ++c) {
            int col = wc * 32 + c * 16 + lc;
            float bv = b3[col];
#pragma unroll
            for (int a = 0; a < 4; ++a)
#pragma unroll
                for (int r = 0; r < 4; ++r) acc[a][c][r] += bv;
        }
        float ps1[4][4], ps2[4][4];
#pragma unroll
        for (int a = 0; a < 4; ++a)
#pragma unroll
            for (int r = 0; r < 4; ++r) { ps1[a][r] = 0.f; ps2[a][r] = 0.f; }
#pragma unroll
        for (int a = 0; a < 4; ++a)
#pragma unroll
            for (int c = 0; c < NT; ++c)
#pragma unroll
                for (int r = 0; r < 4; ++r) {
                    float v = acc[a][c][r];
                    ps1[a][r] += v;
                    ps2[a][r] = __fmaf_rn(v, v, ps2[a][r]);
                }
        ln_stats(ps1, ps2, 1.f / 128);

        float gcol[NT], bcol[NT];
#pragma unroll
        for (int c = 0; c < NT; ++c) {
            int col = wc * 32 + c * 16 + lc;
            gcol[c] = gh[col];
            bcol[c] = bh[col];
        }
        float asum = 0.f;
#pragma unroll
        for (int a = 0; a < 4; ++a)
#pragma unroll
            for (int r = 0; r < 4; ++r) {
                int rl = wr * 64 + a * 16 + lg * 4 + r;
                float mu = lnMR[rl], rs = lnMR[128 + rl];
                int sx = (rl >> 1) & 3;
                int rowb = 16384 + rl * 256;
#pragma unroll
                for (int c = 0; c < NT; ++c) {
                    int col = wc * 32 + c * 16 + lc;
                    float v = (acc[a][c][r] - mu) * rs * gcol[c] + bcol[c];
                    float mz = mish_f(v);
                    asum += fabsf(mz);
                    int byte = rowb + ((col >> 5) << 6) +
                               ((((col >> 3) & 3) ^ sx) << 4) + ((col & 7) << 1);
                    *(unsigned short*)(smem + byte) = f2bf(mz);
                }
            }
#pragma unroll
        for (int m = 1; m < 64; m <<= 1) asum += __shfl_xor(asum, m);
        if (lane == 0) wsum[wu] = asum;
        __syncthreads();
        if (tid == 0) {
            float s = 0.f;
            for (int w = 0; w < 8; ++w) s += wsum[w];
            partials[blockIdx.x] = s;
        }
        __syncthreads();
    }

    // ================= GEMM3: h3(128) -> actQ(264/320), LN(g3,b3n), mish =================
    {
        constexpr int NT = 6;
        f32x4 acc[4][NT];
#pragma unroll
        for (int a = 0; a < 4; ++a)
#pragma unroll
            for (int c = 0; c < NT; ++c) acc[a][c] = (f32x4){0.f, 0.f, 0.f, 0.f};

        auto stage3 = [&](int t, int b) {
#pragma unroll
            for (int i = 0; i < 3; ++i) {
                int c = wu + 8 * i;
                const char* g = (const char*)D1p +
                    ((size_t)(c * 16) * 128) * 2 + (size_t)t * 64 + vofD1;
                glds16(g, smem + (65536 + b * 24576 + c * 1024));
            }
        };

        stage3(0, 0);
        __syncthreads();
        for (int t = 0; t < 4; ++t) {
            const int bsel = t & 1;
            if (t + 1 < 4) stage3(t + 1, bsel ^ 1);
            const char* Ab = smem + 16384 + (wr * 64 + lc) * 256 + t * 64 + fswz;
            const char* Bb = smem + 65536 + bsel * 24576 + (wc * 96 + lc) * 64 + fswz;
            bf16x8 afr[4], bfr[NT];
#pragma unroll
            for (int a = 0; a < 4; ++a) afr[a] = *(const bf16x8*)(Ab + a * 16 * 256);
#pragma unroll
            for (int c = 0; c < NT; ++c) bfr[c] = *(const bf16x8*)(Bb + c * 1024);
            __builtin_amdgcn_s_setprio(1);
#pragma unroll
            for (int c = 0; c < NT; ++c)
#pragma unroll
                for (int a = 0; a < 4; ++a)
                    acc[a][c] = __builtin_amdgcn_mfma_f32_16x16x32_bf16(afr[a], bfr[c], acc[a][c], 0, 0, 0);
            __builtin_amdgcn_s_setprio(0);
            __syncthreads();
        }

        float ps1[4][4], ps2[4][4];
#pragma unroll
        for (int a = 0; a < 4; ++a)
#pragma unroll
            for (int r = 0; r < 4; ++r) { ps1[a][r] = 0.f; ps2[a][r] = 0.f; }
#pragma unroll
        for (int a = 0; a < 4; ++a)
#pragma unroll
            for (int c = 0; c < NT; ++c)
#pragma unroll
                for (int r = 0; r < 4; ++r) {
                    float v = acc[a][c][r];
                    ps1[a][r] += v;
                    ps2[a][r] = __fmaf_rn(v, v, ps2[a][r]);
                }
        ln_stats(ps1, ps2, 1.f / 264);

        float gcol[NT], bcol[NT];
#pragma unroll
        for (int c = 0; c < NT; ++c) {
            int col = wc * 96 + c * 16 + lc;
            gcol[c] = (col < 264) ? g3[col] : 0.f;
            bcol[c] = (col < 264) ? b3n[col] : 0.f;
        }
#pragma unroll
        for (int a = 0; a < 4; ++a)
#pragma unroll
            for (int r = 0; r < 4; ++r) {
                int rl = wr * 64 + a * 16 + lg * 4 + r;
                float mu = lnMR[rl], rs = lnMR[128 + rl];
                size_t rowoff = (size_t)(row0 + rl) * 320;
#pragma unroll
                for (int c = 0; c < NT; ++c) {
                    int col = wc * 96 + c * 16 + lc;
                    if (col < 320) {
                        unsigned short outv = 0;
                        if (col < 264) {
                            float v = (acc[a][c][r] - mu) * rs * gcol[c] + bcol[c];
                            outv = f2bf(mish_f(v));
                        }
                        actQ[rowoff + col] = outv;
                    }
                }
            }
    }
}

// ---------------- deterministic reduction of |latent| partials ----------------
__global__ void reduce_abs(const float* __restrict__ partials, float* __restrict__ out) {
    __shared__ float sm[256];
    float s = 0.f;
    for (int i = threadIdx.x; i < 512; i += 256) s += partials[i];  // fixed order
    sm[threadIdx.x] = s;
    __syncthreads();
    for (int step = 128; step > 0; step >>= 1) {
        if (threadIdx.x < step) sm[threadIdx.x] += sm[threadIdx.x + step];
        __syncthreads();
    }
    if (threadIdx.x == 0) out[0] = sm[0];
}

extern "C" void kernel_launch(void* const* d_in, const int* in_sizes, int n_in,
                              void* d_out, int out_size, void* d_ws, size_t ws_size,
                              hipStream_t stream)
{
    const float* x   = (const float*)d_in[0];
    const float* W1  = (const float*)d_in[1];
    const float* g1  = (const float*)d_in[2];
    const float* b1  = (const float*)d_in[3];
    const float* W2  = (const float*)d_in[4];
    const float* g2  = (const float*)d_in[5];
    const float* b2  = (const float*)d_in[6];
    const float* W3  = (const float*)d_in[7];
    const float* b3  = (const float*)d_in[8];
    const float* gh  = (const float*)d_in[9];
    const float* bh  = (const float*)d_in[10];
    const float* D1  = (const float*)d_in[11];
    const float* g3  = (const float*)d_in[12];
    const float* b3n = (const float*)d_in[13];
    const float* D2  = (const float*)d_in[14];
    const float* g4  = (const float*)d_in[15];
    const float* b4  = (const float*)d_in[16];
    const float* D3  = (const float*)d_in[17];
    const float* bo  = (const float*)d_in[18];

    char* ws = (char*)d_ws;
    size_t off = 0;
    auto alloc = [&](size_t bytes) -> char* {
        char* p = ws + off;
        off += (bytes + 255) & ~(size_t)255;
        return p;
    };
    unsigned short* W1p = (unsigned short*)alloc((size_t)512 * 832 * 2);
    unsigned short* W2p = (unsigned short*)alloc((size_t)384 * 512 * 2);
    unsigned short* W3p = (unsigned short*)alloc((size_t)128 * 288 * 2);
    unsigned short* D1p = (unsigned short*)alloc((size_t)384 * 128 * 2);
    unsigned short* D2p = (unsigned short*)alloc((size_t)512 * 320 * 2);
    unsigned short* D3p = (unsigned short*)alloc((size_t)896 * 512 * 2);
    unsigned short* actP = (unsigned short*)alloc((size_t)B_ROWS * 512 * 2);
    unsigned short* actQ = (unsigned short*)alloc((size_t)B_ROWS * 320 * 2);
    float* partials = (float*)alloc(512 * 4);

    CvtArgs ca;
    ca.src[0] = W1; ca.dst[0] = W1p; ca.O[0] = 512; ca.K[0] = 784; ca.KP[0] = 832;
    ca.src[1] = W2; ca.dst[1] = W2p; ca.O[1] = 264; ca.K[1] = 512; ca.KP[1] = 512;
    ca.src[2] = W3; ca.dst[2] = W3p; ca.O[2] = 128; ca.K[2] = 264; ca.KP[2] = 288;
    ca.src[3] = D1; ca.dst[3] = D1p; ca.O[3] = 264; ca.K[3] = 128; ca.KP[3] = 128;
    ca.src[4] = D2; ca.dst[4] = D2p; ca.O[4] = 512; ca.K[4] = 264; ca.KP[4] = 320;
    ca.src[5] = D3; ca.dst[5] = D3p; ca.O[5] = 784; ca.K[5] = 512; ca.KP[5] = 512;
    ca.base[0] = 0;    ca.base[1] = 512;  ca.base[2] = 896;
    ca.base[3] = 1024; ca.base[4] = 1408; ca.base[5] = 1920; ca.base[6] = 2816;
    wpad_kernel<<<2816, 256, 0, stream>>>(ca);

    const int NB = B_ROWS / 128;  // 512 row-tiles

    // L1: x[.,784] @ W1^T -> 512, LN, mish   (v9, LDS 160K)
    layer9<832, 784, 512, 512, 512, 13, true,  false, false, true,  false>
        <<<NB, 512, 0, stream>>>(x, W1p, g1, b1, nullptr, actP, nullptr);
    // L2+L3+L4 fused: actP -> (LDS h2 -> h3) -> actQ (stride 320) + |latent| partials
    trio<<<NB, 512, 0, stream>>>(actP, W2p, W3p, D1p,
                                 g2, b2, gh, bh, b3, g3, b3n, actQ, partials);
    // L5: 320 -> 512, LN, mish  (v9, LDS 160K)
    layer9<320, 320, 512, 512, 512, 5,  false, false, false, true,  false>
        <<<NB, 512, 0, stream>>>(actQ, D2p, g4, b4, nullptr, actP, nullptr);
    // L6: 512 -> 784, two col-passes; grid (2, NB) so both passes of a
    // row-tile are dispatch-adjacent (L2 sharing of actP re-read)
    dim3 g6(2, NB);
    layer9<512, 512, 448, 784, 784, 8,  false, true,  false, false, true>
        <<<g6, 512, 0, stream>>>(actP, D3p, nullptr, nullptr, bo, d_out, nullptr);

    reduce_abs<<<1, 256, 0, stream>>>(partials, (float*)d_out + (size_t)B_ROWS * 784);
}

// Round 18
// 401.828 us; speedup vs baseline: 1.6140x; 1.0092x over previous
//
#include <hip/hip_runtime.h>

// AutoEncoder v18, bf16 MFMA (gfx950).
// = v17 (best) with trio optimized: G2 switched to BK=64 (5 steps, W3 KP=320,
// h2 stride 640 w/ 8-slot swizzle), G3 single-shot (stage all of D1 once,
// one barrier). L1/L5/L6(SWAPGRID) unchanged.

typedef short bf16x8 __attribute__((ext_vector_type(8)));
typedef float f32x4  __attribute__((ext_vector_type(4)));

#define B_ROWS 65536
#define EPS_LN 1e-5f

static __device__ __forceinline__ unsigned short f2bf(float f) {
    union { float f; unsigned u; } v; v.f = f;
    unsigned r = v.u + 0x7FFFu + ((v.u >> 16) & 1u);   // RNE
    return (unsigned short)(r >> 16);
}

static __device__ __forceinline__ float mish_f(float x) {
    if (x > 15.f) return x;
    float u = __expf(x);
    float p = __fmaf_rn(u, u, 2.f * u);
    return x * (p / (p + 2.f));
}

// direct global->LDS, 16B per lane; LDS base must be wave-uniform
static __device__ __forceinline__ void glds16(const void* g, void* l) {
    typedef __attribute__((address_space(3))) unsigned lds_u32;
    typedef __attribute__((address_space(1))) const unsigned glb_u32;
    lds_u32* lp = (lds_u32*)l;
    unsigned lofs = __builtin_amdgcn_readfirstlane((unsigned)(unsigned long long)lp);
    lp = (lds_u32*)(unsigned long long)lofs;
    __builtin_amdgcn_global_load_lds((glb_u32*)g, lp, 16, 0, 0);
}

// ---------------- padded weight fp32->bf16 conversion ----------------
struct CvtArgs {
    const float* src[6];
    unsigned short* dst[6];
    int O[6], K[6], KP[6];
    int base[7];
};

__global__ void wpad_kernel(CvtArgs a) {
    int b = blockIdx.x;
    int seg = 0;
    while (b >= a.base[seg + 1]) ++seg;
    int r = b - a.base[seg];
    int O = a.O[seg], K = a.K[seg], KP = a.KP[seg];
    const float* s = a.src[seg];
    unsigned short* d = a.dst[seg];
    for (int c = threadIdx.x; c < KP; c += 256) {
        unsigned short v = 0;
        if (r < O && c < K) v = f2bf(s[(size_t)r * K + c]);
        d[(size_t)r * KP + c] = v;
    }
}

// ---------------- v9 fused layer kernel (BK=64) ----------------
template<int KP, int ASTR, int BN, int OREAL, int OSTRIDE, int NKT,
         bool SRCF32, bool HASBIAS, bool ABS, bool LN, bool SWAPGRID>
__global__ __launch_bounds__(512, 2)
void layer9(const void* __restrict__ Asrc,
            const unsigned short* __restrict__ Wp,
            const float* __restrict__ gam,
            const float* __restrict__ bet,
            const float* __restrict__ bias,
            void* __restrict__ Aout,
            float* __restrict__ partials)
{
    constexpr int NT   = BN / 64;
    constexpr int NCHW = BN / 8;
    constexpr int NCH  = NCHW + (SRCF32 ? 0 : 16);
    constexpr int MAXC = (NCH + 7) / 8;
    constexpr int ABY  = 128 * 128;
    constexpr int WBY  = BN * 128;

    __shared__ __align__(16) char smem[2 * ABY + 2 * WBY];

    const int tid  = threadIdx.x;
    const int lane = tid & 63;
    const int wu   = __builtin_amdgcn_readfirstlane(tid >> 6);
    const int wr = wu >> 2, wc = wu & 3;
    const int lg = lane >> 4, lc = lane & 15;
    const int row0  = (SWAPGRID ? blockIdx.y : blockIdx.x) * 128;
    const int cbase = LN ? 0 : (SWAPGRID ? blockIdx.x : blockIdx.y) * BN;

    const int crow = lane >> 3;
    const int sg   = (lane & 7) ^ crow;
    const size_t vofW = ((size_t)crow * KP + (size_t)(sg << 3)) * 2;
    const size_t vofA = ((size_t)crow * ASTR + (size_t)(sg << 3)) * 2;

    auto stage = [&](int t, int b) {
#pragma unroll
        for (int i = 0; i < MAXC; ++i) {
            int c = wu + 8 * i;
            if (c < NCHW) {
                const char* g = (const char*)Wp +
                    ((size_t)(cbase + c * 8) * KP) * 2 + (size_t)t * 128 + vofW;
                glds16(g, smem + (2 * ABY + b * WBY + c * 1024));
            } else if (c < NCH) {
                int ca = c - NCHW;
                const char* g = (const char*)Asrc +
                    ((size_t)(row0 + ca * 8) * ASTR) * 2 + (size_t)t * 128 + vofA;
                glds16(g, smem + (b * ABY + ca * 1024));
            }
        }
    };

    const int ar = tid >> 2, as = tid & 3;
    const float* axp = (const float*)Asrc + (size_t)(row0 + ar) * ASTR + as * 16;
    float4 rA[4];
#pragma unroll
    for (int j = 0; j < 4; ++j) rA[j] = make_float4(0, 0, 0, 0);

    auto loadA1 = [&](int t) {
#pragma unroll
        for (int j = 0; j < 4; ++j) {
            int c0 = t * 64 + as * 16 + j * 4;
            rA[j] = (c0 + 3 < 784) ? *(const float4*)(axp + t * 64 + j * 4)
                                   : make_float4(0, 0, 0, 0);
        }
    };
    auto pubA = [&](int b) {
        union { unsigned short us[8]; uint4 v; } u0, u1;
        u0.us[0] = f2bf(rA[0].x); u0.us[1] = f2bf(rA[0].y);
        u0.us[2] = f2bf(rA[0].z); u0.us[3] = f2bf(rA[0].w);
        u0.us[4] = f2bf(rA[1].x); u0.us[5] = f2bf(rA[1].y);
        u0.us[6] = f2bf(rA[1].z); u0.us[7] = f2bf(rA[1].w);
        u1.us[0] = f2bf(rA[2].x); u1.us[1] = f2bf(rA[2].y);
        u1.us[2] = f2bf(rA[2].z); u1.us[3] = f2bf(rA[2].w);
        u1.us[4] = f2bf(rA[3].x); u1.us[5] = f2bf(rA[3].y);
        u1.us[6] = f2bf(rA[3].z); u1.us[7] = f2bf(rA[3].w);
        int s0 = as * 2, rb = b * ABY + ar * 128, rx = ar & 7;
        *(uint4*)(smem + rb + (((s0    ) ^ rx) << 4)) = u0.v;
        *(uint4*)(smem + rb + (((s0 + 1) ^ rx) << 4)) = u1.v;
    };

    stage(0, 0);
    if constexpr (SRCF32) { loadA1(0); pubA(0); }
    __syncthreads();

    f32x4 acc[4][NT];
#pragma unroll
    for (int a = 0; a < 4; ++a)
#pragma unroll
        for (int c = 0; c < NT; ++c) acc[a][c] = (f32x4){0.f, 0.f, 0.f, 0.f};

    const int f0 = ((lg ^ (lc & 7)) << 4);

    for (int t = 0; t < NKT; ++t) {
        const int bsel = t & 1;
        if (t + 1 < NKT) {
            stage(t + 1, bsel ^ 1);
            if constexpr (SRCF32) loadA1(t + 1);
        }
        const char* Ab = smem + bsel * ABY + (wr * 64 + lc) * 128;
        const char* Bb = smem + 2 * ABY + bsel * WBY + (wc * NT * 16 + lc) * 128;
#pragma unroll
        for (int h = 0; h < 2; ++h) {
            const int fh = f0 ^ (h << 6);
            bf16x8 afr[4], bfr[NT];
#pragma unroll
            for (int a = 0; a < 4; ++a)
                afr[a] = *(const bf16x8*)(Ab + a * 2048 + fh);
#pragma unroll
            for (int c = 0; c < NT; ++c)
                bfr[c] = *(const bf16x8*)(Bb + c * 2048 + fh);
            __builtin_amdgcn_s_setprio(1);
#pragma unroll
            for (int c = 0; c < NT; ++c)
#pragma unroll
                for (int a = 0; a < 4; ++a)
                    acc[a][c] = __builtin_amdgcn_mfma_f32_16x16x32_bf16(afr[a], bfr[c], acc[a][c], 0, 0, 0);
            __builtin_amdgcn_s_setprio(0);
        }
        if constexpr (SRCF32) { if (t + 1 < NKT) pubA(bsel ^ 1); }
        __syncthreads();
    }

    if constexpr (LN) {
        if constexpr (HASBIAS) {
#pragma unroll
            for (int c = 0; c < NT; ++c) {
                int col = wc * NT * 16 + c * 16 + lc;
                float bv = (col < OREAL) ? bias[col] : 0.f;
#pragma unroll
                for (int a = 0; a < 4; ++a)
#pragma unroll
                    for (int r = 0; r < 4; ++r) acc[a][c][r] += bv;
            }
        }
        float ps1[4][4], ps2[4][4];
#pragma unroll
        for (int a = 0; a < 4; ++a)
#pragma unroll
            for (int r = 0; r < 4; ++r) { ps1[a][r] = 0.f; ps2[a][r] = 0.f; }
#pragma unroll
        for (int a = 0; a < 4; ++a)
#pragma unroll
            for (int c = 0; c < NT; ++c)
#pragma unroll
                for (int r = 0; r < 4; ++r) {
                    float v = acc[a][c][r];
                    ps1[a][r] += v;
                    ps2[a][r] = __fmaf_rn(v, v, ps2[a][r]);
                }
#pragma unroll
        for (int m = 1; m < 16; m <<= 1)
#pragma unroll
            for (int a = 0; a < 4; ++a)
#pragma unroll
                for (int r = 0; r < 4; ++r) {
                    ps1[a][r] += __shfl_xor(ps1[a][r], m);
                    ps2[a][r] += __shfl_xor(ps2[a][r], m);
                }

        float* lnP  = (float*)smem;
        float* lnMR = (float*)(smem + 4096);
        float* wsum = (float*)(smem + 5120);

        if (lc == 0) {
#pragma unroll
            for (int a = 0; a < 4; ++a)
#pragma unroll
                for (int r = 0; r < 4; ++r) {
                    int row = wr * 64 + a * 16 + lg * 4 + r;
                    lnP[row * 4 + wc]       = ps1[a][r];
                    lnP[512 + row * 4 + wc] = ps2[a][r];
                }
        }
        __syncthreads();
        if (tid < 128) {
            float s1 = lnP[tid * 4] + lnP[tid * 4 + 1] + lnP[tid * 4 + 2] + lnP[tid * 4 + 3];
            float s2 = lnP[512 + tid * 4] + lnP[512 + tid * 4 + 1] +
                       lnP[512 + tid * 4 + 2] + lnP[512 + tid * 4 + 3];
            float mu = s1 * (1.f / OREAL);
            float var = fmaxf(s2 * (1.f / OREAL) - mu * mu, 0.f);
            lnMR[tid]       = mu;
            lnMR[128 + tid] = rsqrtf(var + EPS_LN);
        }
        __syncthreads();

        float gcol[NT], bcol[NT];
#pragma unroll
        for (int c = 0; c < NT; ++c) {
            int col = wc * NT * 16 + c * 16 + lc;
            gcol[c] = (col < OREAL) ? gam[col] : 0.f;
            bcol[c] = (col < OREAL) ? bet[col] : 0.f;
        }

        float asum = 0.f;
        unsigned short* outp = (unsigned short*)Aout;
#pragma unroll
        for (int a = 0; a < 4; ++a)
#pragma unroll
            for (int r = 0; r < 4; ++r) {
                int rl = wr * 64 + a * 16 + lg * 4 + r;
                float mu = lnMR[rl], rs = lnMR[128 + rl];
                size_t rowoff = (size_t)(row0 + rl) * OSTRIDE;
#pragma unroll
                for (int c = 0; c < NT; ++c) {
                    int col = wc * NT * 16 + c * 16 + lc;
                    if (col < OSTRIDE) {
                        unsigned short outv = 0;
                        if (col < OREAL) {
                            float v = (acc[a][c][r] - mu) * rs * gcol[c] + bcol[c];
                            float mz = mish_f(v);
                            if (ABS) asum += fabsf(mz);
                            outv = f2bf(mz);
                        }
                        outp[rowoff + col] = outv;
                    }
                }
            }

        if constexpr (ABS) {
#pragma unroll
            for (int m = 1; m < 64; m <<= 1) asum += __shfl_xor(asum, m);
            if (lane == 0) wsum[wu] = asum;
            __syncthreads();
            if (tid == 0) {
                float s = 0.f;
                for (int w = 0; w < 8; ++w) s += wsum[w];
                partials[blockIdx.x] = s;
            }
        }
    } else {
        float* outp = (float*)Aout;
#pragma unroll
        for (int c = 0; c < NT; ++c) {
            int col = cbase + wc * NT * 16 + c * 16 + lc;
            bool ok = col < OREAL;
            float bv = ok ? bias[col] : 0.f;
#pragma unroll
            for (int a = 0; a < 4; ++a)
#pragma unroll
                for (int r = 0; r < 4; ++r) {
                    if (ok) {
                        int rl = wr * 64 + a * 16 + lg * 4 + r;
                        float v = acc[a][c][r] + bv;
                        outp[(size_t)(row0 + rl) * OSTRIDE + col] = 1.f / (1.f + __expf(-v));
                    }
                }
        }
    }
}

// ---------------- trio kernel: L2+L3+L4 fused, activations in LDS ----------------
// LDS map: G1: A dbuf [0,16K) W2 dbuf [16K,64K) h2 -> [64K,144K) stride 640
//          G2: W3 dbuf [0,32K) (BK=64, KP=320)  h3 -> [32K,64K) stride 256
//          G3: D1 whole [64K,160K) single-shot  out -> actQ
//          LN scratch [152K,157K) (dead-region reuse, barrier-separated)
#define H2B  65536
#define H3B  32768
#define D1B  65536
#define LNB  155648

__global__ __launch_bounds__(512, 2)
void trio(const unsigned short* __restrict__ actP,
          const unsigned short* __restrict__ W2p,   // [384][512]
          const unsigned short* __restrict__ W3p,   // [128][320]
          const unsigned short* __restrict__ D1p,   // [384][128]
          const float* __restrict__ g2, const float* __restrict__ b2,
          const float* __restrict__ gh, const float* __restrict__ bh,
          const float* __restrict__ b3,
          const float* __restrict__ g3, const float* __restrict__ b3n,
          unsigned short* __restrict__ actQ,        // [B][320]
          float* __restrict__ partials)
{
    __shared__ __align__(16) char smem[163840];

    const int tid  = threadIdx.x;
    const int lane = tid & 63;
    const int wu   = __builtin_amdgcn_readfirstlane(tid >> 6);
    const int wr = wu >> 2, wc = wu & 3;
    const int lg = lane >> 4, lc = lane & 15;
    const int row0 = blockIdx.x * 128;

    // BK=32 chunk swizzle (G1 staging, 64B rows / 4 slots)
    const int sgl = (lane & 3) ^ ((lane >> 3) & 3);
    const size_t vofA  = ((size_t)(lane >> 2) * 512 + (size_t)(sgl << 3)) * 2;
    const size_t vofW2 = vofA;
    // BK=64 chunk swizzle (G2 W3 staging, 128B rows / 8 slots), KP=320
    const int crow8 = lane >> 3;
    const int sg8   = (lane & 7) ^ crow8;
    const size_t vofW3 = ((size_t)crow8 * 320 + (size_t)(sg8 << 3)) * 2;
    // G3 D1 staging: chunk = 4 rows x 256B; per-tile 8-slot swizzle by (row&7)
    const int rr4 = lane >> 4, s16 = lane & 15;
    const size_t vofD1e = (size_t)(rr4 * 256 + ((s16 >> 3) << 7) + (((s16 & 7) ^ rr4) << 4));
    const size_t vofD1o = (size_t)(rr4 * 256 + ((s16 >> 3) << 7) + (((s16 & 7) ^ rr4 ^ 4) << 4));

    const int fswz = ((lg ^ ((lc >> 1) & 3)) << 4);   // G1 frag reads (64B rows)
    const int f0   = ((lg ^ (lc & 7)) << 4);          // G2/G3 frag reads (128B rows)

    float* lnP  = (float*)(smem + LNB);
    float* lnMR = (float*)(smem + LNB + 4096);
    float* wsum = (float*)(smem + LNB + 5120);

    auto ln_stats = [&](float ps1[4][4], float ps2[4][4], float invO) {
#pragma unroll
        for (int m = 1; m < 16; m <<= 1)
#pragma unroll
            for (int a = 0; a < 4; ++a)
#pragma unroll
                for (int r = 0; r < 4; ++r) {
                    ps1[a][r] += __shfl_xor(ps1[a][r], m);
                    ps2[a][r] += __shfl_xor(ps2[a][r], m);
                }
        if (lc == 0) {
#pragma unroll
            for (int a = 0; a < 4; ++a)
#pragma unroll
                for (int r = 0; r < 4; ++r) {
                    int row = wr * 64 + a * 16 + lg * 4 + r;
                    lnP[row * 4 + wc]       = ps1[a][r];
                    lnP[512 + row * 4 + wc] = ps2[a][r];
                }
        }
        __syncthreads();
        if (tid < 128) {
            float s1 = lnP[tid * 4] + lnP[tid * 4 + 1] + lnP[tid * 4 + 2] + lnP[tid * 4 + 3];
            float s2 = lnP[512 + tid * 4] + lnP[512 + tid * 4 + 1] +
                       lnP[512 + tid * 4 + 2] + lnP[512 + tid * 4 + 3];
            float mu = s1 * invO;
            float var = fmaxf(s2 * invO - mu * mu, 0.f);
            lnMR[tid]       = mu;
            lnMR[128 + tid] = rsqrtf(var + EPS_LN);
        }
        __syncthreads();
    };

    // ========== G1: actP(512) -> h2(264, stored 320-wide str 640), LN, mish ==========
    {
        constexpr int NT = 6;                      // BN 384
        f32x4 acc[4][NT];
#pragma unroll
        for (int a = 0; a < 4; ++a)
#pragma unroll
            for (int c = 0; c < NT; ++c) acc[a][c] = (f32x4){0.f, 0.f, 0.f, 0.f};

        auto stage1 = [&](int t, int b) {
#pragma unroll
            for (int i = 0; i < 4; ++i) {
                int c = wu + 8 * i;                // 0..31
                if (c < 24) {
                    const char* g = (const char*)W2p +
                        ((size_t)(c * 16) * 512) * 2 + (size_t)t * 64 + vofW2;
                    glds16(g, smem + (16384 + b * 24576 + c * 1024));
                } else {
                    int ca = c - 24;
                    const char* g = (const char*)actP +
                        ((size_t)(row0 + ca * 16) * 512) * 2 + (size_t)t * 64 + vofA;
                    glds16(g, smem + (b * 8192 + ca * 1024));
                }
            }
        };

        stage1(0, 0);
        __syncthreads();
        for (int t = 0; t < 16; ++t) {
            const int bsel = t & 1;
            if (t + 1 < 16) stage1(t + 1, bsel ^ 1);
            const char* Ab = smem + bsel * 8192 + (wr * 64 + lc) * 64 + fswz;
            const char* Bb = smem + 16384 + bsel * 24576 + (wc * 96 + lc) * 64 + fswz;
            bf16x8 afr[4], bfr[NT];
#pragma unroll
            for (int a = 0; a < 4; ++a) afr[a] = *(const bf16x8*)(Ab + a * 1024);
#pragma unroll
            for (int c = 0; c < NT; ++c) bfr[c] = *(const bf16x8*)(Bb + c * 1024);
            __builtin_amdgcn_s_setprio(1);
#pragma unroll
            for (int c = 0; c < NT; ++c)
#pragma unroll
                for (int a = 0; a < 4; ++a)
                    acc[a][c] = __builtin_amdgcn_mfma_f32_16x16x32_bf16(afr[a], bfr[c], acc[a][c], 0, 0, 0);
            __builtin_amdgcn_s_setprio(0);
            __syncthreads();
        }

        float ps1[4][4], ps2[4][4];
#pragma unroll
        for (int a = 0; a < 4; ++a)
#pragma unroll
            for (int r = 0; r < 4; ++r) { ps1[a][r] = 0.f; ps2[a][r] = 0.f; }
#pragma unroll
        for (int a = 0; a < 4; ++a)
#pragma unroll
            for (int c = 0; c < NT; ++c)
#pragma unroll
                for (int r = 0; r < 4; ++r) {
                    float v = acc[a][c][r];
                    ps1[a][r] += v;
                    ps2[a][r] = __fmaf_rn(v, v, ps2[a][r]);
                }
        ln_stats(ps1, ps2, 1.f / 264);

        float gcol[NT], bcol[NT];
#pragma unroll
        for (int c = 0; c < NT; ++c) {
            int col = wc * 96 + c * 16 + lc;
            gcol[c] = (col < 264) ? g2[col] : 0.f;
            bcol[c] = (col < 264) ? b2[col] : 0.f;
        }
        // h2 write: stride 640, 8-slot swizzle per 128B tile by (row&7)
#pragma unroll
        for (int a = 0; a < 4; ++a)
#pragma unroll
            for (int r = 0; r < 4; ++r) {
                int rl = wr * 64 + a * 16 + lg * 4 + r;
                float mu = lnMR[rl], rs = lnMR[128 + rl];
                int rx = rl & 7;
                int rowb = H2B + rl * 640;
#pragma unroll
                for (int c = 0; c < NT; ++c) {
                    int col = wc * 96 + c * 16 + lc;
                    if (col < 320) {
                        unsigned short outv = 0;
                        if (col < 264) {
                            float v = (acc[a][c][r] - mu) * rs * gcol[c] + bcol[c];
                            outv = f2bf(mish_f(v));
                        }
                        int byte = rowb + ((col >> 6) << 7) +
                                   ((((col >> 3) & 7) ^ rx) << 4) + ((col & 7) << 1);
                        *(unsigned short*)(smem + byte) = outv;
                    }
                }
            }
        __syncthreads();
    }

    // ========== G2: h2(320) -> h3(128), BK=64 x 5 steps, +b3, LN, mish, |.| ==========
    {
        constexpr int NT = 2;                      // BN 128
        f32x4 acc[4][NT];
#pragma unroll
        for (int a = 0; a < 4; ++a)
#pragma unroll
            for (int c = 0; c < NT; ++c) acc[a][c] = (f32x4){0.f, 0.f, 0.f, 0.f};

        auto stage2 = [&](int t, int b) {
#pragma unroll
            for (int i = 0; i < 2; ++i) {
                int c = wu + 8 * i;                // 0..15 (16 chunks of 8 rows)
                const char* g = (const char*)W3p +
                    ((size_t)(c * 8) * 320) * 2 + (size_t)t * 128 + vofW3;
                glds16(g, smem + (b * 16384 + c * 1024));
            }
        };

        stage2(0, 0);
        __syncthreads();
        for (int t = 0; t < 5; ++t) {
            const int bsel = t & 1;
            if (t + 1 < 5) stage2(t + 1, bsel ^ 1);
            const char* Ab = smem + H2B + (wr * 64 + lc) * 640 + t * 128;
            const char* Bb = smem + bsel * 16384 + (wc * 32 + lc) * 128;
#pragma unroll
            for (int h = 0; h < 2; ++h) {
                const int fh = f0 ^ (h << 6);
                bf16x8 afr[4], bfr[NT];
#pragma unroll
                for (int a = 0; a < 4; ++a) afr[a] = *(const bf16x8*)(Ab + a * 16 * 640 + fh);
#pragma unroll
                for (int c = 0; c < NT; ++c) bfr[c] = *(const bf16x8*)(Bb + c * 2048 + fh);
                __builtin_amdgcn_s_setprio(1);
#pragma unroll
                for (int c = 0; c < NT; ++c)
#pragma unroll
                    for (int a = 0; a < 4; ++a)
                        acc[a][c] = __builtin_amdgcn_mfma_f32_16x16x32_bf16(afr[a], bfr[c], acc[a][c], 0, 0, 0);
                __builtin_amdgcn_s_setprio(0);
            }
            __syncthreads();
        }

#pragma unroll
        for (int c = 0; c < NT; ++c) {
            int col = wc * 32 + c * 16 + lc;
            float bv = b3[col];
#pragma unroll
            for (int a = 0; a < 4; ++a)
#pragma unroll
                for (int r = 0; r < 4; ++r) acc[a][c][r] += bv;
        }
        float ps1[4][4], ps2[4][4];
#pragma unroll
        for (int a = 0; a < 4; ++a)
#pragma unroll
            for (int r = 0; r < 4; ++r) { ps1[a][r] = 0.f; ps2[a][r] = 0.f; }
#pragma unroll
        for (int a = 0; a < 4; ++a)
#pragma unroll
            for (int c = 0; c < NT; ++c)
#pragma unroll
                for (int r = 0; r < 4; ++r) {
                    float v = acc[a][c][r];
                    ps1[a][r] += v;
                    ps2[a][r] = __fmaf_rn(v, v, ps2[a][r]);
                }
        ln_stats(ps1, ps2, 1.f / 128);

        float gcol[NT], bcol[NT];
#pragma unroll
        for (int c = 0; c < NT; ++c) {
            int col = wc * 32 + c * 16 + lc;
            gcol[c] = gh[col];
            bcol[c] = bh[col];
        }
        float asum = 0.f;
#pragma unroll
        for (int a = 0; a < 4; ++a)
#pragma unroll
            for (int r = 0; r < 4; ++r) {
                int rl = wr * 64 + a * 16 + lg * 4 + r;
                float mu = lnMR[rl], rs = lnMR[128 + rl];
                int rx = rl & 7;
                int rowb = H3B + rl * 256;
#pragma unroll
                for (int c = 0; c < NT; ++c) {
                    int col = wc * 32 + c * 16 + lc;
                    float v = (acc[a][c][r] - mu) * rs * gcol[c] + bcol[c];
                    float mz = mish_f(v);
                    asum += fabsf(mz);
                    int byte = rowb + ((col >> 6) << 7) +
                               ((((col >> 3) & 7) ^ rx) << 4) + ((col & 7) << 1);
                    *(unsigned short*)(smem + byte) = f2bf(mz);
                }
            }
#pragma unroll
        for (int m = 1; m < 64; m <<= 1) asum += __shfl_xor(asum, m);
        if (lane == 0) wsum[wu] = asum;
        __syncthreads();
        if (tid == 0) {
            float s = 0.f;
            for (int w = 0; w < 8; ++w) s += wsum[w];
            partials[blockIdx.x] = s;
        }
        __syncthreads();
    }

    // ========== G3: h3(128) -> actQ(264/320), single-shot (D1 fully staged) ==========
    {
        constexpr int NT = 6;                      // BN 384
        f32x4 acc[4][NT];
#pragma unroll
        for (int a = 0; a < 4; ++a)
#pragma unroll
            for (int c = 0; c < NT; ++c) acc[a][c] = (f32x4){0.f, 0.f, 0.f, 0.f};

        // stage all 96 KB of D1 (96 chunks of 4 rows x 256B), 12 per wave
#pragma unroll
        for (int i = 0; i < 12; ++i) {
            int c = wu + 8 * i;                    // 0..95
            const char* g = (const char*)D1p + (size_t)c * 1024 +
                            ((c & 1) ? vofD1o : vofD1e);
            glds16(g, smem + (D1B + c * 1024));
        }
        __syncthreads();

        // K=128: 2 tiles of 64 x 2 halves, 24 MFMA each = 96 MFMA, one cluster
#pragma unroll
        for (int tt = 0; tt < 2; ++tt) {
            const char* Ab = smem + H3B + (wr * 64 + lc) * 256 + tt * 128;
            const char* Bb = smem + D1B + (wc * 96 + lc) * 256 + tt * 128;
#pragma unroll
            for (int h = 0; h < 2; ++h) {
                const int fh = f0 ^ (h << 6);
                bf16x8 afr[4], bfr[NT];
#pragma unroll
                for (int a = 0; a < 4; ++a) afr[a] = *(const bf16x8*)(Ab + a * 16 * 256 + fh);
#pragma unroll
                for (int c = 0; c < NT; ++c) bfr[c] = *(const bf16x8*)(Bb + c * 16 * 256 + fh);
                __builtin_amdgcn_s_setprio(1);
#pragma unroll
                for (int c = 0; c < NT; ++c)
#pragma unroll
                    for (int a = 0; a < 4; ++a)
                        acc[a][c] = __builtin_amdgcn_mfma_f32_16x16x32_bf16(afr[a], bfr[c], acc[a][c], 0, 0, 0);
                __builtin_amdgcn_s_setprio(0);
            }
        }
        __syncthreads();   // all D1/h3 reads done before LN scratch reuse

        float ps1[4][4], ps2[4][4];
#pragma unroll
        for (int a = 0; a < 4; ++a)
#pragma unroll
            for (int r = 0; r < 4; ++r) { ps1[a][r] = 0.f; ps2[a][r] = 0.f; }
#pragma unroll
        for (int a = 0; a < 4; ++a)
#pragma unroll
            for (int c = 0; c < NT; ++c)
#pragma unroll
                for (int r = 0; r < 4; ++r) {
                    float v = acc[a][c][r];
                    ps1[a][r] += v;
                    ps2[a][r] = __fmaf_rn(v, v, ps2[a][r]);
                }
        ln_stats(ps1, ps2, 1.f / 264);

        float gcol[NT], bcol[NT];
#pragma unroll
        for (int c = 0; c < NT; ++c) {
            int col = wc * 96 + c * 16 + lc;
            gcol[c] = (col < 264) ? g3[col] : 0.f;
            bcol[c] = (col < 264) ? b3n[col] : 0.f;
        }
#pragma unroll
        for (int a = 0; a < 4; ++a)
#pragma unroll
            for (int r = 0; r < 4; ++r) {
                int rl = wr * 64 + a * 16 + lg * 4 + r;
                float mu = lnMR[rl], rs = lnMR[128 + rl];
                size_t rowoff = (size_t)(row0 + rl) * 320;
#pragma unroll
                for (int c = 0; c < NT; ++c) {
                    int col = wc * 96 + c * 16 + lc;
                    if (col < 320) {
                        unsigned short outv = 0;
                        if (col < 264) {
                            float v = (acc[a][c][r] - mu) * rs * gcol[c] + bcol[c];
                            outv = f2bf(mish_f(v));
                        }
                        actQ[rowoff + col] = outv;
                    }
                }
            }
    }
}

// ---------------- deterministic reduction of |latent| partials ----------------
__global__ void reduce_abs(const float* __restrict__ partials, float* __restrict__ out) {
    __shared__ float sm[256];
    float s = 0.f;
    for (int i = threadIdx.x; i < 512; i += 256) s += partials[i];  // fixed order
    sm[threadIdx.x] = s;
    __syncthreads();
    for (int step = 128; step > 0; step >>= 1) {
        if (threadIdx.x < step) sm[threadIdx.x] += sm[threadIdx.x + step];
        __syncthreads();
    }
    if (threadIdx.x == 0) out[0] = sm[0];
}

extern "C" void kernel_launch(void* const* d_in, const int* in_sizes, int n_in,
                              void* d_out, int out_size, void* d_ws, size_t ws_size,
                              hipStream_t stream)
{
    const float* x   = (const float*)d_in[0];
    const float* W1  = (const float*)d_in[1];
    const float* g1  = (const float*)d_in[2];
    const float* b1  = (const float*)d_in[3];
    const float* W2  = (const float*)d_in[4];
    const float* g2  = (const float*)d_in[5];
    const float* b2  = (const float*)d_in[6];
    const float* W3  = (const float*)d_in[7];
    const float* b3  = (const float*)d_in[8];
    const float* gh  = (const float*)d_in[9];
    const float* bh  = (const float*)d_in[10];
    const float* D1  = (const float*)d_in[11];
    const float* g3  = (const float*)d_in[12];
    const float* b3n = (const float*)d_in[13];
    const float* D2  = (const float*)d_in[14];
    const float* g4  = (const float*)d_in[15];
    const float* b4  = (const float*)d_in[16];
    const float* D3  = (const float*)d_in[17];
    const float* bo  = (const float*)d_in[18];

    char* ws = (char*)d_ws;
    size_t off = 0;
    auto alloc = [&](size_t bytes) -> char* {
        char* p = ws + off;
        off += (bytes + 255) & ~(size_t)255;
        return p;
    };
    unsigned short* W1p = (unsigned short*)alloc((size_t)512 * 832 * 2);
    unsigned short* W2p = (unsigned short*)alloc((size_t)384 * 512 * 2);
    unsigned short* W3p = (unsigned short*)alloc((size_t)128 * 320 * 2);
    unsigned short* D1p = (unsigned short*)alloc((size_t)384 * 128 * 2);
    unsigned short* D2p = (unsigned short*)alloc((size_t)512 * 320 * 2);
    unsigned short* D3p = (unsigned short*)alloc((size_t)896 * 512 * 2);
    unsigned short* actP = (unsigned short*)alloc((size_t)B_ROWS * 512 * 2);
    unsigned short* actQ = (unsigned short*)alloc((size_t)B_ROWS * 320 * 2);
    float* partials = (float*)alloc(512 * 4);

    CvtArgs ca;
    ca.src[0] = W1; ca.dst[0] = W1p; ca.O[0] = 512; ca.K[0] = 784; ca.KP[0] = 832;
    ca.src[1] = W2; ca.dst[1] = W2p; ca.O[1] = 264; ca.K[1] = 512; ca.KP[1] = 512;
    ca.src[2] = W3; ca.dst[2] = W3p; ca.O[2] = 128; ca.K[2] = 264; ca.KP[2] = 320;
    ca.src[3] = D1; ca.dst[3] = D1p; ca.O[3] = 264; ca.K[3] = 128; ca.KP[3] = 128;
    ca.src[4] = D2; ca.dst[4] = D2p; ca.O[4] = 512; ca.K[4] = 264; ca.KP[4] = 320;
    ca.src[5] = D3; ca.dst[5] = D3p; ca.O[5] = 784; ca.K[5] = 512; ca.KP[5] = 512;
    ca.base[0] = 0;    ca.base[1] = 512;  ca.base[2] = 896;
    ca.base[3] = 1024; ca.base[4] = 1408; ca.base[5] = 1920; ca.base[6] = 2816;
    wpad_kernel<<<2816, 256, 0, stream>>>(ca);

    const int NB = B_ROWS / 128;  // 512 row-tiles

    // L1: x[.,784] @ W1^T -> 512, LN, mish   (v9, LDS 160K)
    layer9<832, 784, 512, 512, 512, 13, true,  false, false, true,  false>
        <<<NB, 512, 0, stream>>>(x, W1p, g1, b1, nullptr, actP, nullptr);
    // L2+L3+L4 fused (optimized trio)
    trio<<<NB, 512, 0, stream>>>(actP, W2p, W3p, D1p,
                                 g2, b2, gh, bh, b3, g3, b3n, actQ, partials);
    // L5: 320 -> 512, LN, mish  (v9, LDS 160K)
    layer9<320, 320, 512, 512, 512, 5,  false, false, false, true,  false>
        <<<NB, 512, 0, stream>>>(actQ, D2p, g4, b4, nullptr, actP, nullptr);
    // L6: 512 -> 784, two col-passes; grid (2, NB) for L2-paired A re-read
    dim3 g6(2, NB);
    layer9<512, 512, 448, 784, 784, 8,  false, true,  false, false, true>
        <<<g6, 512, 0, stream>>>(actP, D3p, nullptr, nullptr, bo, d_out, nullptr);

    reduce_abs<<<1, 256, 0, stream>>>(partials, (float*)d_out + (size_t)B_ROWS * 784);
}